// Round 1
// baseline (2518.267 us; speedup 1.0000x reference)
//
#include <hip/hip_runtime.h>
#include <math.h>

#define D 128
#define H 8
#define C 16
#define ED 10
#define FF 512
#define BN 32

__device__ __forceinline__ unsigned fkey(float f) {
  unsigned b = __float_as_uint(f);
  return (b & 0x80000000u) ? ~b : (b | 0x80000000u);
}
__device__ __forceinline__ float funkey(unsigned u) {
  unsigned b = (u & 0x80000000u) ? (u & 0x7fffffffu) : ~u;
  return __uint_as_float(b);
}

// out[n][d] = x[n][:] @ W[:,d] + b[d]   (W row-major [D][D])
__global__ void gemm128(const float* __restrict__ x, const float* __restrict__ W,
                        const float* __restrict__ b, float* __restrict__ out, int n) {
  __shared__ float Ws[D * D];
  for (int i = threadIdx.x; i < D * D; i += blockDim.x) Ws[i] = W[i];
  __syncthreads();
  int ln = threadIdx.x >> 5;        // 0..7 local node
  int d4 = (threadIdx.x & 31) * 4;  // 0..124
  for (int base = blockIdx.x * 8; base < n; base += gridDim.x * 8) {
    int node = base + ln;
    if (node < n) {
      const float* xr = x + (size_t)node * D;
      float4 acc = make_float4(0.f, 0.f, 0.f, 0.f);
#pragma unroll 8
      for (int kk = 0; kk < D; ++kk) {
        float xv = xr[kk];
        const float4 w = *reinterpret_cast<const float4*>(&Ws[kk * D + d4]);
        acc.x = fmaf(xv, w.x, acc.x);
        acc.y = fmaf(xv, w.y, acc.y);
        acc.z = fmaf(xv, w.z, acc.z);
        acc.w = fmaf(xv, w.w, acc.w);
      }
      const float4 bb = *reinterpret_cast<const float4*>(&b[d4]);
      acc.x += bb.x; acc.y += bb.y; acc.z += bb.z; acc.w += bb.w;
      *reinterpret_cast<float4*>(&out[(size_t)node * D + d4]) = acc;
    }
  }
}

// pass A: alpha[e,h] = q[dst,h,:]·(k[src,h,:] + (attr@We)[h,:]) / 4 ; segment-max via atomicMax
__global__ void edge_alpha(const int* __restrict__ src, const int* __restrict__ dst,
                           const float* __restrict__ attr, const float* __restrict__ We,
                           const float* __restrict__ q, const float* __restrict__ k,
                           float* __restrict__ alpha, unsigned* __restrict__ amaxU, int E) {
  __shared__ float WeS[ED * D];
  for (int i = threadIdx.x; i < ED * D; i += blockDim.x) WeS[i] = We[i];
  __syncthreads();
  int t = blockIdx.x * blockDim.x + threadIdx.x;
  int e = t >> 3;
  if (e >= E) return;
  int h = t & 7;
  int s = src[e], dd = dst[e];
  float a[ED];
#pragma unroll
  for (int j = 0; j < ED; ++j) a[j] = attr[e * ED + j];
  const float* qd = q + (size_t)dd * D + h * C;
  const float* ks = k + (size_t)s * D + h * C;
  float acc = 0.f;
#pragma unroll
  for (int c = 0; c < C; ++c) {
    float ec = 0.f;
#pragma unroll
    for (int j = 0; j < ED; ++j) ec = fmaf(a[j], WeS[j * D + h * C + c], ec);
    acc = fmaf(qd[c], ks[c] + ec, acc);
  }
  acc *= 0.25f;
  alpha[t] = acc;
  atomicMax(&amaxU[dd * H + h], fkey(acc));
}

// pass B: denom[dst,h] += exp(a-m); att[dst,d] += exp(a-m)*(v[src,d]+e_d)  (unnormalized)
__global__ void edge_msg(const int* __restrict__ src, const int* __restrict__ dst,
                         const float* __restrict__ attr, const float* __restrict__ We,
                         const float* __restrict__ v, const float* __restrict__ alpha,
                         const unsigned* __restrict__ amaxU, float* __restrict__ denom,
                         float* __restrict__ att, int E) {
  __shared__ float WeS[ED * D];
  for (int i = threadIdx.x; i < ED * D; i += blockDim.x) WeS[i] = We[i];
  __syncthreads();
  long t = (long)blockIdx.x * blockDim.x + threadIdx.x;
  int e = (int)(t >> 7);
  if (e >= E) return;
  int d = (int)(t & 127);
  int h = d >> 4;
  int s = src[e], dd = dst[e];
  float m = funkey(amaxU[dd * H + h]);
  float ex = expf(alpha[e * H + h] - m);
  if ((d & 15) == 0) atomicAdd(&denom[dd * H + h], ex);
  float ec = 0.f;
#pragma unroll
  for (int j = 0; j < ED; ++j) ec = fmaf(attr[e * ED + j], WeS[j * D + d], ec);
  float msg = ex * (v[(size_t)s * D + d] + ec);
  atomicAdd(&att[(size_t)dd * D + d], msg);
}

// per node: normalize attention, beta-gate skip, +x residual -> h (stored in d_out);
// accumulate per-feature sum(h), sum(h^2)
__global__ void node_finalize(const float* __restrict__ x, const float* __restrict__ att,
                              const float* __restrict__ denom, const float* __restrict__ xr,
                              const float* __restrict__ Wbeta, float* __restrict__ h,
                              float* __restrict__ sums, int n) {
  __shared__ float red[2];
  int d = threadIdx.x;  // 128 threads
  float wb0 = Wbeta[d], wb1 = Wbeta[D + d], wb2 = Wbeta[2 * D + d];
  float sum_h = 0.f, sum_h2 = 0.f;
  for (int node = blockIdx.x; node < n; node += gridDim.x) {
    float den = denom[node * H + (d >> 4)];
    float o = att[(size_t)node * D + d] / (den + 1e-16f);
    float xrd = xr[(size_t)node * D + d];
    float pb = o * wb0 + xrd * wb1 + (o - xrd) * wb2;
#pragma unroll
    for (int off = 32; off > 0; off >>= 1) pb += __shfl_down(pb, off, 64);
    if ((threadIdx.x & 63) == 0) red[threadIdx.x >> 6] = pb;
    __syncthreads();
    float bin = red[0] + red[1];
    float beta = 1.f / (1.f + expf(-bin));
    float hd = x[(size_t)node * D + d] + beta * xrd + (1.f - beta) * o;
    h[(size_t)node * D + d] = hd;
    sum_h += hd;
    sum_h2 += hd * hd;
    __syncthreads();
  }
  atomicAdd(&sums[d], sum_h);
  atomicAdd(&sums[D + d], sum_h2);
}

// finalize GraphNorm stats -> per-feature scale/shift
__global__ void gn_stats(const float* __restrict__ sums, const float* __restrict__ gn_w,
                         const float* __restrict__ gn_b, const float* __restrict__ gn_ms,
                         float* __restrict__ scsh, float inv_n) {
  int d = threadIdx.x;
  float mean = sums[d] * inv_n;
  float ex2 = sums[D + d] * inv_n;
  float ms = gn_ms[d];
  // E[(h - ms*mean)^2] = E[h^2] - 2*ms*mean^2 + ms^2*mean^2
  float var = ex2 - 2.f * ms * mean * mean + ms * ms * mean * mean;
  float inv = 1.f / sqrtf(var + 1e-5f);
  float scale = gn_w[d] * inv;
  float shift = gn_b[d] - ms * mean * scale;
  scsh[d] = scale;
  scsh[D + d] = shift;
}

// FFN: hn = h*scale+shift; out = hn + gelu(hn@W1+b1)@W2 + b2
// h lives in the same buffer as out (d_out); tile is loaded to LDS before overwrite.
__global__ __launch_bounds__(256) void ffn_kernel(
    const float* __restrict__ hbuf, const float* __restrict__ scsh,
    const float* __restrict__ W1, const float* __restrict__ b1,
    const float* __restrict__ W2, const float* __restrict__ b2,
    float* __restrict__ out, int n) {
  __shared__ float hn[BN][D];   // 16 KB
  __shared__ float tt[BN][FF];  // 64 KB
  __shared__ float sc[2 * D];
  for (int i = threadIdx.x; i < 2 * D; i += 256) sc[i] = scsh[i];
  __syncthreads();
  int base = blockIdx.x * BN;
  for (int idx = threadIdx.x; idx < BN * D; idx += 256) {
    int nl = idx >> 7, d = idx & 127;
    int node = base + nl;
    float hv = (node < n) ? hbuf[(size_t)node * D + d] : 0.f;
    hn[nl][d] = hv * sc[d] + sc[D + d];
  }
  __syncthreads();
  // t = gelu(hn @ W1 + b1): each thread computes 4 consecutive f
  for (int idx = threadIdx.x; idx < BN * (FF / 4); idx += 256) {
    int nl = idx / (FF / 4);
    int f4 = (idx % (FF / 4)) * 4;
    float4 acc = *reinterpret_cast<const float4*>(&b1[f4]);
#pragma unroll 4
    for (int kk = 0; kk < D; ++kk) {
      float hv = hn[nl][kk];
      const float4 w = *reinterpret_cast<const float4*>(&W1[kk * FF + f4]);
      acc.x = fmaf(hv, w.x, acc.x);
      acc.y = fmaf(hv, w.y, acc.y);
      acc.z = fmaf(hv, w.z, acc.z);
      acc.w = fmaf(hv, w.w, acc.w);
    }
    const float inv_sqrt2 = 0.70710678118654752440f;
    tt[nl][f4 + 0] = 0.5f * acc.x * (1.f + erff(acc.x * inv_sqrt2));
    tt[nl][f4 + 1] = 0.5f * acc.y * (1.f + erff(acc.y * inv_sqrt2));
    tt[nl][f4 + 2] = 0.5f * acc.z * (1.f + erff(acc.z * inv_sqrt2));
    tt[nl][f4 + 3] = 0.5f * acc.w * (1.f + erff(acc.w * inv_sqrt2));
  }
  __syncthreads();
  // out = hn + t @ W2 + b2: each thread computes 4 consecutive d
  for (int idx = threadIdx.x; idx < BN * (D / 4); idx += 256) {
    int nl = idx / (D / 4);
    int d4 = (idx % (D / 4)) * 4;
    int node = base + nl;
    if (node >= n) continue;
    float4 acc = *reinterpret_cast<const float4*>(&b2[d4]);
#pragma unroll 4
    for (int ff = 0; ff < FF; ++ff) {
      float tv = tt[nl][ff];
      const float4 w = *reinterpret_cast<const float4*>(&W2[ff * D + d4]);
      acc.x = fmaf(tv, w.x, acc.x);
      acc.y = fmaf(tv, w.y, acc.y);
      acc.z = fmaf(tv, w.z, acc.z);
      acc.w = fmaf(tv, w.w, acc.w);
    }
    acc.x += hn[nl][d4 + 0];
    acc.y += hn[nl][d4 + 1];
    acc.z += hn[nl][d4 + 2];
    acc.w += hn[nl][d4 + 3];
    *reinterpret_cast<float4*>(&out[(size_t)node * D + d4]) = acc;
  }
}

extern "C" void kernel_launch(void* const* d_in, const int* in_sizes, int n_in,
                              void* d_out, int out_size, void* d_ws, size_t ws_size,
                              hipStream_t stream) {
  const float* x     = (const float*)d_in[0];
  const int*   ei    = (const int*)d_in[1];
  const float* attr  = (const float*)d_in[2];
  const float* Wq    = (const float*)d_in[3];
  const float* bq    = (const float*)d_in[4];
  const float* Wk    = (const float*)d_in[5];
  const float* bk    = (const float*)d_in[6];
  const float* Wv    = (const float*)d_in[7];
  const float* bv    = (const float*)d_in[8];
  const float* We    = (const float*)d_in[9];
  const float* Wskip = (const float*)d_in[10];
  const float* bskip = (const float*)d_in[11];
  const float* Wbeta = (const float*)d_in[12];
  const float* gn_w  = (const float*)d_in[13];
  const float* gn_b  = (const float*)d_in[14];
  const float* gn_ms = (const float*)d_in[15];
  const float* W1    = (const float*)d_in[16];
  const float* b1    = (const float*)d_in[17];
  const float* W2    = (const float*)d_in[18];
  const float* b2    = (const float*)d_in[19];

  const int n = in_sizes[0] / D;
  const int E = in_sizes[1] / 2;
  const int* src = ei;
  const int* dst = ei + E;
  const size_t ND = (size_t)n * D;
  const size_t NH = (size_t)n * H;

  float* ws = (float*)d_ws;
  float* q     = ws;
  float* k     = q + ND;
  float* v     = k + ND;
  float* xr    = v + ND;
  float* alpha = xr + ND;                     // E*H
  float* att   = alpha + (size_t)E * H;       // N*D  (zeroed)
  float* denom = att + ND;                    // N*H  (zeroed)
  unsigned* amaxU = (unsigned*)(denom + NH);  // N*H  (zeroed: key 0 < key(-inf))
  float* sums  = (float*)(amaxU + NH);        // 2*D  (zeroed)
  float* scsh  = sums + 2 * D;                // 2*D

  // zero accumulators (att, denom, amaxU, sums are contiguous)
  hipMemsetAsync(att, 0, (ND + 2 * NH + 2 * D) * sizeof(float), stream);

  int gq = (n + 7) / 8;
  gemm128<<<gq, 256, 0, stream>>>(x, Wq, bq, q, n);
  gemm128<<<gq, 256, 0, stream>>>(x, Wk, bk, k, n);
  gemm128<<<gq, 256, 0, stream>>>(x, Wv, bv, v, n);
  gemm128<<<gq, 256, 0, stream>>>(x, Wskip, bskip, xr, n);

  edge_alpha<<<((size_t)E * H + 255) / 256, 256, 0, stream>>>(src, dst, attr, We, q, k,
                                                              alpha, amaxU, E);
  edge_msg<<<((size_t)E * D + 255) / 256, 256, 0, stream>>>(src, dst, attr, We, v, alpha,
                                                            amaxU, denom, att, E);

  node_finalize<<<2048, 128, 0, stream>>>(x, att, denom, xr, Wbeta, (float*)d_out, sums, n);
  gn_stats<<<1, 128, 0, stream>>>(sums, gn_w, gn_b, gn_ms, scsh, 1.f / (float)n);
  ffn_kernel<<<(n + BN - 1) / BN, 256, 0, stream>>>((const float*)d_out, scsh, W1, b1, W2,
                                                    b2, (float*)d_out, n);
}

// Round 2
// 1171.685 us; speedup vs baseline: 2.1493x; 2.1493x over previous
//
#include <hip/hip_runtime.h>
#include <hip/hip_fp16.h>
#include <math.h>

#define D 128
#define H 8
#define C 16
#define ED 10
#define FF 512

typedef __attribute__((ext_vector_type(4))) float f32x4;
typedef __attribute__((ext_vector_type(8))) short bf16x8;

__device__ __forceinline__ unsigned fkey(float f) {
  unsigned b = __float_as_uint(f);
  return (b & 0x80000000u) ? ~b : (b | 0x80000000u);
}
__device__ __forceinline__ float funkey(unsigned u) {
  unsigned b = (u & 0x80000000u) ? (u & 0x7fffffffu) : ~u;
  return __uint_as_float(b);
}
__device__ __forceinline__ ushort f2bf(float f) {
  unsigned u = __float_as_uint(f);
  unsigned r = u + 0x7fffu + ((u >> 16) & 1u);
  return (ushort)(r >> 16);
}

// ---------------- weight prep: transpose + cast to bf16 ----------------
__global__ void prep_weights(const float* __restrict__ Wq, const float* __restrict__ Wk,
                             const float* __restrict__ Wv, const float* __restrict__ Wskip,
                             const float* __restrict__ bq, const float* __restrict__ bk,
                             const float* __restrict__ bv, const float* __restrict__ bskip,
                             const float* __restrict__ W1, const float* __restrict__ W2,
                             ushort* __restrict__ Wcat_t, float* __restrict__ bcat,
                             ushort* __restrict__ W1t, ushort* __restrict__ W2t) {
  int t = blockIdx.x * blockDim.x + threadIdx.x;  // 0..65535
  if (t >= 4 * D * D) return;
  // Wcat_t[w][c][k] = W_w[k][c]
  {
    int w = t >> 14, c = (t >> 7) & 127, kk = t & 127;
    const float* W = (w == 0) ? Wq : (w == 1) ? Wk : (w == 2) ? Wv : Wskip;
    Wcat_t[t] = f2bf(W[kk * D + c]);
  }
  // W1t[f][k] = W1[k][f]   (f = t>>7, k = t&127)
  {
    int f = t >> 7, kk = t & 127;
    W1t[t] = f2bf(W1[kk * FF + f]);
  }
  // W2t[c][f] = W2[f][c]   (c = t>>9, f = t&511)
  {
    int c = t >> 9, f = t & 511;
    W2t[t] = f2bf(W2[f * D + c]);
  }
  if (t < 4 * D) {
    int w = t >> 7;
    const float* b = (w == 0) ? bq : (w == 1) ? bk : (w == 2) ? bv : bskip;
    bcat[t] = b[t & 127];
  }
}

__device__ __forceinline__ bf16x8 load_a_f32(const float* p) {
  float4 x0 = *reinterpret_cast<const float4*>(p);
  float4 x1 = *reinterpret_cast<const float4*>(p + 4);
  bf16x8 r;
  r[0] = (short)f2bf(x0.x); r[1] = (short)f2bf(x0.y);
  r[2] = (short)f2bf(x0.z); r[3] = (short)f2bf(x0.w);
  r[4] = (short)f2bf(x1.x); r[5] = (short)f2bf(x1.y);
  r[6] = (short)f2bf(x1.z); r[7] = (short)f2bf(x1.w);
  return r;
}

// ---------------- fused q/k/v/xr GEMM: [N,128] @ 4x[128,128] ----------------
// block = 64 rows; wave w -> output buffer w (128 cols). K=128.
__global__ __launch_bounds__(256) void gemm_in(
    const float* __restrict__ x, const ushort* __restrict__ Wcat_t,
    const float* __restrict__ bcat, float* __restrict__ q, float* __restrict__ k,
    float* __restrict__ v, float* __restrict__ xr, int n) {
  int wv = threadIdx.x >> 6;
  int l = threadIdx.x & 63;
  int lr = l & 15, lg = l >> 4;
  int r0 = blockIdx.x * 64;
  float* outb = (wv == 0) ? q : (wv == 1) ? k : (wv == 2) ? v : xr;
  const ushort* Wt = Wcat_t + wv * D * D;
  f32x4 acc[4][8];
#pragma unroll
  for (int m = 0; m < 4; ++m)
#pragma unroll
    for (int nn = 0; nn < 8; ++nn) acc[m][nn] = (f32x4)0.f;
#pragma unroll
  for (int kb = 0; kb < 4; ++kb) {
    int k0 = kb * 32 + lg * 8;
    bf16x8 a[4];
#pragma unroll
    for (int m = 0; m < 4; ++m) {
      int row = r0 + m * 16 + lr;
      row = min(row, n - 1);
      a[m] = load_a_f32(x + (size_t)row * D + k0);
    }
    bf16x8 b[8];
#pragma unroll
    for (int nn = 0; nn < 8; ++nn)
      b[nn] = *reinterpret_cast<const bf16x8*>(Wt + (nn * 16 + lr) * D + k0);
#pragma unroll
    for (int m = 0; m < 4; ++m)
#pragma unroll
      for (int nn = 0; nn < 8; ++nn)
        acc[m][nn] = __builtin_amdgcn_mfma_f32_16x16x32_bf16(a[m], b[nn], acc[m][nn], 0, 0, 0);
  }
#pragma unroll
  for (int m = 0; m < 4; ++m)
#pragma unroll
    for (int nn = 0; nn < 8; ++nn) {
      int col = nn * 16 + lr;
      float bb = bcat[wv * D + col];
#pragma unroll
      for (int j = 0; j < 4; ++j) {
        int row = r0 + m * 16 + lg * 4 + j;
        if (row < n) outb[(size_t)row * D + col] = acc[m][nn][j] + bb;
      }
    }
}

// ---------------- edge pass A ----------------
__global__ void edge_alpha(const int* __restrict__ src, const int* __restrict__ dst,
                           const float* __restrict__ attr, const float* __restrict__ We,
                           const float* __restrict__ q, const float* __restrict__ k,
                           __half* __restrict__ alpha, unsigned* __restrict__ amaxU, int E) {
  __shared__ float WeS[ED * D];
  for (int i = threadIdx.x; i < ED * D; i += blockDim.x) WeS[i] = We[i];
  __syncthreads();
  int t = blockIdx.x * blockDim.x + threadIdx.x;
  int e = t >> 3;
  if (e >= E) return;
  int h = t & 7;
  int s = src[e], dd = dst[e];
  float a[ED];
#pragma unroll
  for (int j = 0; j < ED; ++j) a[j] = attr[e * ED + j];
  const float* qd = q + (size_t)dd * D + h * C;
  const float* ks = k + (size_t)s * D + h * C;
  float acc = 0.f;
#pragma unroll
  for (int c = 0; c < C; ++c) {
    float ec = 0.f;
#pragma unroll
    for (int j = 0; j < ED; ++j) ec = fmaf(a[j], WeS[j * D + h * C + c], ec);
    acc = fmaf(qd[c], ks[c] + ec, acc);
  }
  acc *= 0.25f;
  alpha[t] = __float2half(acc);
  atomicMax(&amaxU[dd * H + h], fkey(acc));
}

// ---------------- edge pass B ----------------
__global__ void edge_msg(const int* __restrict__ src, const int* __restrict__ dst,
                         const float* __restrict__ attr, const float* __restrict__ We,
                         const float* __restrict__ v, const __half* __restrict__ alpha,
                         const unsigned* __restrict__ amaxU, float* __restrict__ denom,
                         float* __restrict__ att, int E) {
  __shared__ float WeS[ED * D];
  for (int i = threadIdx.x; i < ED * D; i += blockDim.x) WeS[i] = We[i];
  __syncthreads();
  long t = (long)blockIdx.x * blockDim.x + threadIdx.x;
  int e = (int)(t >> 7);
  if (e >= E) return;
  int d = (int)(t & 127);
  int h = d >> 4;
  int s = src[e], dd = dst[e];
  float m = funkey(amaxU[dd * H + h]);
  float ex = expf(__half2float(alpha[e * H + h]) - m);
  if ((d & 15) == 0) atomicAdd(&denom[dd * H + h], ex);
  float ec = 0.f;
#pragma unroll
  for (int j = 0; j < ED; ++j) ec = fmaf(attr[e * ED + j], WeS[j * D + d], ec);
  float msg = ex * (v[(size_t)s * D + d] + ec);
  atomicAdd(&att[(size_t)dd * D + d], msg);
}

// ---------------- node finalize: normalize, beta gate, residual, GN sums ----------------
__global__ void node_finalize(const float* __restrict__ x, const float* __restrict__ att,
                              const float* __restrict__ denom, const float* __restrict__ xr,
                              const float* __restrict__ Wbeta, float* __restrict__ h,
                              float* __restrict__ sums, int n) {
  __shared__ float red[2];
  int d = threadIdx.x;  // 128 threads
  float wb0 = Wbeta[d], wb1 = Wbeta[D + d], wb2 = Wbeta[2 * D + d];
  float sum_h = 0.f, sum_h2 = 0.f;
  for (int node = blockIdx.x; node < n; node += gridDim.x) {
    float den = denom[node * H + (d >> 4)];
    float o = att[(size_t)node * D + d] / (den + 1e-16f);
    float xrd = xr[(size_t)node * D + d];
    float pb = o * wb0 + xrd * wb1 + (o - xrd) * wb2;
#pragma unroll
    for (int off = 32; off > 0; off >>= 1) pb += __shfl_down(pb, off, 64);
    if ((threadIdx.x & 63) == 0) red[threadIdx.x >> 6] = pb;
    __syncthreads();
    float bin = red[0] + red[1];
    float beta = 1.f / (1.f + expf(-bin));
    float hd = x[(size_t)node * D + d] + beta * xrd + (1.f - beta) * o;
    h[(size_t)node * D + d] = hd;
    sum_h += hd;
    sum_h2 += hd * hd;
    __syncthreads();
  }
  atomicAdd(&sums[d], sum_h);
  atomicAdd(&sums[D + d], sum_h2);
}

__global__ void gn_stats(const float* __restrict__ sums, const float* __restrict__ gn_w,
                         const float* __restrict__ gn_b, const float* __restrict__ gn_ms,
                         float* __restrict__ scsh, float inv_n) {
  int d = threadIdx.x;
  float mean = sums[d] * inv_n;
  float ex2 = sums[D + d] * inv_n;
  float ms = gn_ms[d];
  float var = ex2 - 2.f * ms * mean * mean + ms * ms * mean * mean;
  float inv = 1.f / sqrtf(var + 1e-5f);
  float scale = gn_w[d] * inv;
  float shift = gn_b[d] - ms * mean * scale;
  scsh[d] = scale;
  scsh[D + d] = shift;
}

// ---------------- FFN GEMM1: t = gelu(hn @ W1 + b1), hn = h*scale+shift ----------------
__global__ __launch_bounds__(256) void ffn1(
    const float* __restrict__ h, const float* __restrict__ scsh,
    const ushort* __restrict__ W1t, const float* __restrict__ b1,
    ushort* __restrict__ tbf, int n) {
  int wv = threadIdx.x >> 6;
  int l = threadIdx.x & 63;
  int lr = l & 15, lg = l >> 4;
  int r0 = blockIdx.x * 64;
  int c0 = wv * 128;
  f32x4 acc[4][8];
#pragma unroll
  for (int m = 0; m < 4; ++m)
#pragma unroll
    for (int nn = 0; nn < 8; ++nn) acc[m][nn] = (f32x4)0.f;
#pragma unroll
  for (int kb = 0; kb < 4; ++kb) {
    int k0 = kb * 32 + lg * 8;
    float4 s0 = *reinterpret_cast<const float4*>(scsh + k0);
    float4 s1 = *reinterpret_cast<const float4*>(scsh + k0 + 4);
    float4 t0 = *reinterpret_cast<const float4*>(scsh + D + k0);
    float4 t1 = *reinterpret_cast<const float4*>(scsh + D + k0 + 4);
    bf16x8 a[4];
#pragma unroll
    for (int m = 0; m < 4; ++m) {
      int row = r0 + m * 16 + lr;
      row = min(row, n - 1);
      const float* p = h + (size_t)row * D + k0;
      float4 x0 = *reinterpret_cast<const float4*>(p);
      float4 x1 = *reinterpret_cast<const float4*>(p + 4);
      bf16x8 r;
      r[0] = (short)f2bf(x0.x * s0.x + t0.x);
      r[1] = (short)f2bf(x0.y * s0.y + t0.y);
      r[2] = (short)f2bf(x0.z * s0.z + t0.z);
      r[3] = (short)f2bf(x0.w * s0.w + t0.w);
      r[4] = (short)f2bf(x1.x * s1.x + t1.x);
      r[5] = (short)f2bf(x1.y * s1.y + t1.y);
      r[6] = (short)f2bf(x1.z * s1.z + t1.z);
      r[7] = (short)f2bf(x1.w * s1.w + t1.w);
      a[m] = r;
    }
    bf16x8 b[8];
#pragma unroll
    for (int nn = 0; nn < 8; ++nn)
      b[nn] = *reinterpret_cast<const bf16x8*>(W1t + (c0 + nn * 16 + lr) * D + k0);
#pragma unroll
    for (int m = 0; m < 4; ++m)
#pragma unroll
      for (int nn = 0; nn < 8; ++nn)
        acc[m][nn] = __builtin_amdgcn_mfma_f32_16x16x32_bf16(a[m], b[nn], acc[m][nn], 0, 0, 0);
  }
  const float inv_sqrt2 = 0.70710678118654752440f;
#pragma unroll
  for (int m = 0; m < 4; ++m)
#pragma unroll
    for (int nn = 0; nn < 8; ++nn) {
      int col = c0 + nn * 16 + lr;
      float bb = b1[col];
#pragma unroll
      for (int j = 0; j < 4; ++j) {
        int row = r0 + m * 16 + lg * 4 + j;
        if (row < n) {
          float val = acc[m][nn][j] + bb;
          val = 0.5f * val * (1.f + erff(val * inv_sqrt2));
          tbf[(size_t)row * FF + col] = f2bf(val);
        }
      }
    }
}

// ---------------- FFN GEMM2: out = hn + t @ W2 + b2 (in place on h/d_out) ----------------
__global__ __launch_bounds__(256) void ffn2(
    const ushort* __restrict__ tbf, const ushort* __restrict__ W2t,
    const float* __restrict__ b2, const float* __restrict__ scsh,
    float* __restrict__ h, int n) {
  int wv = threadIdx.x >> 6;
  int l = threadIdx.x & 63;
  int lr = l & 15, lg = l >> 4;
  int r0 = blockIdx.x * 64;
  f32x4 acc[4][2];
#pragma unroll
  for (int m = 0; m < 4; ++m)
#pragma unroll
    for (int nn = 0; nn < 2; ++nn) acc[m][nn] = (f32x4)0.f;
#pragma unroll 4
  for (int kb = 0; kb < 16; ++kb) {
    int k0 = kb * 32 + lg * 8;
    bf16x8 a[4];
#pragma unroll
    for (int m = 0; m < 4; ++m) {
      int row = r0 + m * 16 + lr;
      row = min(row, n - 1);
      a[m] = *reinterpret_cast<const bf16x8*>(tbf + (size_t)row * FF + k0);
    }
    bf16x8 b[2];
#pragma unroll
    for (int nn = 0; nn < 2; ++nn)
      b[nn] = *reinterpret_cast<const bf16x8*>(W2t + (wv * 32 + nn * 16 + lr) * FF + k0);
#pragma unroll
    for (int m = 0; m < 4; ++m)
#pragma unroll
      for (int nn = 0; nn < 2; ++nn)
        acc[m][nn] = __builtin_amdgcn_mfma_f32_16x16x32_bf16(a[m], b[nn], acc[m][nn], 0, 0, 0);
  }
#pragma unroll
  for (int m = 0; m < 4; ++m)
#pragma unroll
    for (int nn = 0; nn < 2; ++nn) {
      int col = wv * 32 + nn * 16 + lr;
      float bb = b2[col];
      float sc = scsh[col], sh = scsh[D + col];
#pragma unroll
      for (int j = 0; j < 4; ++j) {
        int row = r0 + m * 16 + lg * 4 + j;
        if (row < n) {
          size_t idx = (size_t)row * D + col;
          float hn = h[idx] * sc + sh;
          h[idx] = hn + acc[m][nn][j] + bb;
        }
      }
    }
}

extern "C" void kernel_launch(void* const* d_in, const int* in_sizes, int n_in,
                              void* d_out, int out_size, void* d_ws, size_t ws_size,
                              hipStream_t stream) {
  const float* x     = (const float*)d_in[0];
  const int*   ei    = (const int*)d_in[1];
  const float* attr  = (const float*)d_in[2];
  const float* Wq    = (const float*)d_in[3];
  const float* bq    = (const float*)d_in[4];
  const float* Wk    = (const float*)d_in[5];
  const float* bk    = (const float*)d_in[6];
  const float* Wv    = (const float*)d_in[7];
  const float* bv    = (const float*)d_in[8];
  const float* We    = (const float*)d_in[9];
  const float* Wskip = (const float*)d_in[10];
  const float* bskip = (const float*)d_in[11];
  const float* Wbeta = (const float*)d_in[12];
  const float* gn_w  = (const float*)d_in[13];
  const float* gn_b  = (const float*)d_in[14];
  const float* gn_ms = (const float*)d_in[15];
  const float* W1    = (const float*)d_in[16];
  const float* b1    = (const float*)d_in[17];
  const float* W2    = (const float*)d_in[18];
  const float* b2    = (const float*)d_in[19];

  const int n = in_sizes[0] / D;
  const int E = in_sizes[1] / 2;
  const int* src = ei;
  const int* dst = ei + E;
  const size_t ND = (size_t)n * D;
  const size_t NH = (size_t)n * H;

  float* ws = (float*)d_ws;
  float* q     = ws;                          // ND
  float* kbuf  = q + ND;                      // ND   (q..k region reused as tbf)
  float* v     = kbuf + ND;                   // ND
  float* xr    = v + ND;                      // ND
  float* att   = xr + ND;                     // ND   (zeroed)
  float* denom = att + ND;                    // NH   (zeroed)
  unsigned* amaxU = (unsigned*)(denom + NH);  // NH   (zeroed)
  float* sums  = (float*)(amaxU + NH);        // 2D   (zeroed)
  float* scsh  = sums + 2 * D;                // 2D
  __half* alphah = (__half*)(scsh + 2 * D);   // E*H halves
  ushort* Wcat_t = (ushort*)(alphah + (size_t)E * H);
  ushort* W1t  = Wcat_t + 4 * D * D;
  ushort* W2t  = W1t + D * FF;
  float*  bcat = (float*)(W2t + FF * D);
  ushort* tbf  = (ushort*)q;                  // N*FF bf16, aliases q+k

  hipMemsetAsync(att, 0, (ND + 2 * NH + 2 * D) * sizeof(float), stream);
  prep_weights<<<(4 * D * D + 255) / 256, 256, 0, stream>>>(
      Wq, Wk, Wv, Wskip, bq, bk, bv, bskip, W1, W2, Wcat_t, bcat, W1t, W2t);

  int gm = (n + 63) / 64;
  gemm_in<<<gm, 256, 0, stream>>>(x, Wcat_t, bcat, q, kbuf, v, xr, n);

  edge_alpha<<<((size_t)E * H + 255) / 256, 256, 0, stream>>>(src, dst, attr, We, q, kbuf,
                                                              alphah, amaxU, E);
  edge_msg<<<((size_t)E * D + 255) / 256, 256, 0, stream>>>(src, dst, attr, We, v, alphah,
                                                            amaxU, denom, att, E);

  node_finalize<<<2048, 128, 0, stream>>>(x, att, denom, xr, Wbeta, (float*)d_out, sums, n);
  gn_stats<<<1, 128, 0, stream>>>(sums, gn_w, gn_b, gn_ms, scsh, 1.f / (float)n);

  ffn1<<<gm, 256, 0, stream>>>((const float*)d_out, scsh, W1t, b1, tbf, n);
  ffn2<<<gm, 256, 0, stream>>>(tbf, W2t, b2, scsh, (float*)d_out, n);
}

// Round 3
// 674.528 us; speedup vs baseline: 3.7334x; 1.7370x over previous
//
#include <hip/hip_runtime.h>
#include <math.h>

#define D 128
#define H 8
#define C 16
#define ED 10
#define FF 512

typedef __attribute__((ext_vector_type(4))) float f32x4;
typedef __attribute__((ext_vector_type(8))) short bf16x8;

__device__ __forceinline__ ushort f2bf(float f) {
  unsigned u = __float_as_uint(f);
  unsigned r = u + 0x7fffu + ((u >> 16) & 1u);
  return (ushort)(r >> 16);
}
__device__ __forceinline__ float bf2f(ushort u) {
  return __uint_as_float(((unsigned)u) << 16);
}

// ---------------- weight prep: transpose + cast to bf16 ----------------
__global__ void prep_weights(const float* __restrict__ Wq, const float* __restrict__ Wk,
                             const float* __restrict__ Wv, const float* __restrict__ Wskip,
                             const float* __restrict__ bq, const float* __restrict__ bk,
                             const float* __restrict__ bv, const float* __restrict__ bskip,
                             const float* __restrict__ W1, const float* __restrict__ W2,
                             ushort* __restrict__ Wcat_t, float* __restrict__ bcat,
                             ushort* __restrict__ W1t, ushort* __restrict__ W2t) {
  int t = blockIdx.x * blockDim.x + threadIdx.x;  // 0..65535
  if (t >= 4 * D * D) return;
  {
    int w = t >> 14, c = (t >> 7) & 127, kk = t & 127;
    const float* W = (w == 0) ? Wq : (w == 1) ? Wk : (w == 2) ? Wv : Wskip;
    Wcat_t[t] = f2bf(W[kk * D + c]);
  }
  {
    int f = t >> 7, kk = t & 127;
    W1t[t] = f2bf(W1[kk * FF + f]);
  }
  {
    int c = t >> 9, f = t & 511;
    W2t[t] = f2bf(W2[f * D + c]);
  }
  if (t < 4 * D) {
    int w = t >> 7;
    const float* b = (w == 0) ? bq : (w == 1) ? bk : (w == 2) ? bv : bskip;
    bcat[t] = b[t & 127];
  }
}

__device__ __forceinline__ bf16x8 load_a_f32(const float* p) {
  float4 x0 = *reinterpret_cast<const float4*>(p);
  float4 x1 = *reinterpret_cast<const float4*>(p + 4);
  bf16x8 r;
  r[0] = (short)f2bf(x0.x); r[1] = (short)f2bf(x0.y);
  r[2] = (short)f2bf(x0.z); r[3] = (short)f2bf(x0.w);
  r[4] = (short)f2bf(x1.x); r[5] = (short)f2bf(x1.y);
  r[6] = (short)f2bf(x1.z); r[7] = (short)f2bf(x1.w);
  return r;
}

// ---------------- fused q/k/v/xr GEMM: [N,128] @ 4x[128,128] ----------------
// q,k,v written bf16 (gather tables); xr written f32.
__global__ __launch_bounds__(256) void gemm_in(
    const float* __restrict__ x, const ushort* __restrict__ Wcat_t,
    const float* __restrict__ bcat, ushort* __restrict__ qb, ushort* __restrict__ kb,
    ushort* __restrict__ vb, float* __restrict__ xr, int n) {
  int wv = threadIdx.x >> 6;
  int l = threadIdx.x & 63;
  int lr = l & 15, lg = l >> 4;
  int r0 = blockIdx.x * 64;
  const ushort* Wt = Wcat_t + wv * D * D;
  f32x4 acc[4][8];
#pragma unroll
  for (int m = 0; m < 4; ++m)
#pragma unroll
    for (int nn = 0; nn < 8; ++nn) acc[m][nn] = (f32x4)0.f;
#pragma unroll
  for (int kb2 = 0; kb2 < 4; ++kb2) {
    int k0 = kb2 * 32 + lg * 8;
    bf16x8 a[4];
#pragma unroll
    for (int m = 0; m < 4; ++m) {
      int row = r0 + m * 16 + lr;
      row = min(row, n - 1);
      a[m] = load_a_f32(x + (size_t)row * D + k0);
    }
    bf16x8 b[8];
#pragma unroll
    for (int nn = 0; nn < 8; ++nn)
      b[nn] = *reinterpret_cast<const bf16x8*>(Wt + (nn * 16 + lr) * D + k0);
#pragma unroll
    for (int m = 0; m < 4; ++m)
#pragma unroll
      for (int nn = 0; nn < 8; ++nn)
        acc[m][nn] = __builtin_amdgcn_mfma_f32_16x16x32_bf16(a[m], b[nn], acc[m][nn], 0, 0, 0);
  }
  ushort* ub = (wv == 0) ? qb : (wv == 1) ? kb : vb;
#pragma unroll
  for (int m = 0; m < 4; ++m)
#pragma unroll
    for (int nn = 0; nn < 8; ++nn) {
      int col = nn * 16 + lr;
      float bb = bcat[wv * D + col];
#pragma unroll
      for (int j = 0; j < 4; ++j) {
        int row = r0 + m * 16 + lg * 4 + j;
        if (row < n) {
          float val = acc[m][nn][j] + bb;
          if (wv < 3) ub[(size_t)row * D + col] = f2bf(val);
          else xr[(size_t)row * D + col] = val;
        }
      }
    }
}

// ---------------- CSR build: histogram, scan, scatter ----------------
__global__ void hist_kernel(const int* __restrict__ dst, int* __restrict__ deg, int E) {
  int t = blockIdx.x * blockDim.x + threadIdx.x;
  if (t < E) atomicAdd(&deg[dst[t]], 1);
}

__global__ __launch_bounds__(1024) void scan_kernel(const int* __restrict__ deg,
                                                    int* __restrict__ off, int n) {
  __shared__ int part[1024];
  int t = threadIdx.x;
  int chunk = (n + 1023) / 1024;
  int lo = t * chunk, hi = min(lo + chunk, n);
  int s = 0;
  for (int i = lo; i < hi; ++i) s += deg[i];
  part[t] = s;
  __syncthreads();
  for (int dd = 1; dd < 1024; dd <<= 1) {
    int v = (t >= dd) ? part[t - dd] : 0;
    __syncthreads();
    part[t] += v;
    __syncthreads();
  }
  int excl = (t == 0) ? 0 : part[t - 1];
  for (int i = lo; i < hi; ++i) {
    off[i] = excl;
    excl += deg[i];
  }
}

__global__ void scatter_kernel(const int* __restrict__ dst, const int* __restrict__ off,
                               int* __restrict__ cursor, int* __restrict__ sorted, int E) {
  int t = blockIdx.x * blockDim.x + threadIdx.x;
  if (t >= E) return;
  int dd = dst[t];
  int p = atomicAdd(&cursor[dd], 1);
  sorted[off[dd] + p] = t;
}

// ---------------- fused node-centric attention + beta gate + residual + GN sums -------
// one wave per node; lane l owns features d0=2l, d1=2l+1 (same head = l>>3).
__global__ __launch_bounds__(256) void node_attn(
    const int* __restrict__ src, const int* __restrict__ sorted,
    const int* __restrict__ off, const int* __restrict__ deg,
    const float* __restrict__ attr, const float* __restrict__ We,
    const ushort* __restrict__ qb, const ushort* __restrict__ kb,
    const ushort* __restrict__ vb, const float* __restrict__ xr,
    const float* __restrict__ x, const float* __restrict__ Wbeta,
    float* __restrict__ h, float* __restrict__ sums, int n) {
  __shared__ float2 WeS2[ED * 64];       // WeS2[j*64+l] = (We[j][2l], We[j][2l+1])
  __shared__ float rs_h[4 * D], rs_h2[4 * D];
  for (int i = threadIdx.x; i < ED * 64; i += 256) {
    int j = i >> 6, l = i & 63;
    WeS2[i] = make_float2(We[j * D + 2 * l], We[j * D + 2 * l + 1]);
  }
  __syncthreads();
  int wid = threadIdx.x >> 6;
  int l = threadIdx.x & 63;
  int d0 = 2 * l, d1 = 2 * l + 1;
  float2 wb0 = *reinterpret_cast<const float2*>(Wbeta + d0);
  float2 wb1 = *reinterpret_cast<const float2*>(Wbeta + D + d0);
  float2 wb2 = *reinterpret_cast<const float2*>(Wbeta + 2 * D + d0);
  float s_h0 = 0.f, s_h20 = 0.f, s_h1 = 0.f, s_h21 = 0.f;
  for (int node = blockIdx.x * 4 + wid; node < n; node += gridDim.x * 4) {
    const ushort2 qu = *reinterpret_cast<const ushort2*>(qb + (size_t)node * D + d0);
    float q0 = bf2f(qu.x), q1 = bf2f(qu.y);
    int o0 = off[node], dg = deg[node];
    float m = -1e30f, den = 0.f, acc0 = 0.f, acc1 = 0.f;
    int e_nx = 0, s_nx = 0;
    if (dg > 0) { e_nx = sorted[o0]; s_nx = src[e_nx]; }
    for (int i = 0; i < dg; ++i) {
      int e = e_nx, s = s_nx;
      if (i + 1 < dg) { e_nx = sorted[o0 + i + 1]; s_nx = src[e_nx]; }
      ushort2 ku = *reinterpret_cast<const ushort2*>(kb + (size_t)s * D + d0);
      ushort2 vu = *reinterpret_cast<const ushort2*>(vb + (size_t)s * D + d0);
      const float2* ap = reinterpret_cast<const float2*>(attr + (size_t)e * ED);
      float2 a0 = ap[0], a1 = ap[1], a2 = ap[2], a3 = ap[3], a4 = ap[4];
      float ec0, ec1;
      {
        float2 w;
        w = WeS2[0 * 64 + l]; ec0 = a0.x * w.x;            ec1 = a0.x * w.y;
        w = WeS2[1 * 64 + l]; ec0 = fmaf(a0.y, w.x, ec0);  ec1 = fmaf(a0.y, w.y, ec1);
        w = WeS2[2 * 64 + l]; ec0 = fmaf(a1.x, w.x, ec0);  ec1 = fmaf(a1.x, w.y, ec1);
        w = WeS2[3 * 64 + l]; ec0 = fmaf(a1.y, w.x, ec0);  ec1 = fmaf(a1.y, w.y, ec1);
        w = WeS2[4 * 64 + l]; ec0 = fmaf(a2.x, w.x, ec0);  ec1 = fmaf(a2.x, w.y, ec1);
        w = WeS2[5 * 64 + l]; ec0 = fmaf(a2.y, w.x, ec0);  ec1 = fmaf(a2.y, w.y, ec1);
        w = WeS2[6 * 64 + l]; ec0 = fmaf(a3.x, w.x, ec0);  ec1 = fmaf(a3.x, w.y, ec1);
        w = WeS2[7 * 64 + l]; ec0 = fmaf(a3.y, w.x, ec0);  ec1 = fmaf(a3.y, w.y, ec1);
        w = WeS2[8 * 64 + l]; ec0 = fmaf(a4.x, w.x, ec0);  ec1 = fmaf(a4.x, w.y, ec1);
        w = WeS2[9 * 64 + l]; ec0 = fmaf(a4.y, w.x, ec0);  ec1 = fmaf(a4.y, w.y, ec1);
      }
      float kk0 = bf2f(ku.x) + ec0, kk1 = bf2f(ku.y) + ec1;
      float vv0 = bf2f(vu.x) + ec0, vv1 = bf2f(vu.y) + ec1;
      float p = q0 * kk0 + q1 * kk1;
      p += __shfl_xor(p, 1, 8);
      p += __shfl_xor(p, 2, 8);
      p += __shfl_xor(p, 4, 8);
      float a = p * 0.25f;
      float mn = fmaxf(m, a);
      float sc = __expf(m - mn);
      float ex = __expf(a - mn);
      den = den * sc + ex;
      acc0 = acc0 * sc + ex * vv0;
      acc1 = acc1 * sc + ex * vv1;
      m = mn;
    }
    float inv = 1.f / (den + 1e-16f);
    float oo0 = acc0 * inv, oo1 = acc1 * inv;
    float2 xr2 = *reinterpret_cast<const float2*>(xr + (size_t)node * D + d0);
    float2 x2 = *reinterpret_cast<const float2*>(x + (size_t)node * D + d0);
    float pb = oo0 * wb0.x + xr2.x * wb1.x + (oo0 - xr2.x) * wb2.x
             + oo1 * wb0.y + xr2.y * wb1.y + (oo1 - xr2.y) * wb2.y;
#pragma unroll
    for (int msk = 1; msk < 64; msk <<= 1) pb += __shfl_xor(pb, msk, 64);
    float beta = 1.f / (1.f + __expf(-pb));
    float h0 = x2.x + beta * xr2.x + (1.f - beta) * oo0;
    float h1 = x2.y + beta * xr2.y + (1.f - beta) * oo1;
    *reinterpret_cast<float2*>(h + (size_t)node * D + d0) = make_float2(h0, h1);
    s_h0 += h0; s_h20 += h0 * h0;
    s_h1 += h1; s_h21 += h1 * h1;
  }
  // block-level reduce of GN sums, then 2 atomics per feature per block
  rs_h[wid * D + d0] = s_h0;  rs_h[wid * D + d1] = s_h1;
  rs_h2[wid * D + d0] = s_h20; rs_h2[wid * D + d1] = s_h21;
  __syncthreads();
  if (threadIdx.x < D) {
    int d = threadIdx.x;
    float sh = rs_h[d] + rs_h[D + d] + rs_h[2 * D + d] + rs_h[3 * D + d];
    float sh2 = rs_h2[d] + rs_h2[D + d] + rs_h2[2 * D + d] + rs_h2[3 * D + d];
    atomicAdd(&sums[d], sh);
    atomicAdd(&sums[D + d], sh2);
  }
}

__global__ void gn_stats(const float* __restrict__ sums, const float* __restrict__ gn_w,
                         const float* __restrict__ gn_b, const float* __restrict__ gn_ms,
                         float* __restrict__ scsh, float inv_n) {
  int d = threadIdx.x;
  float mean = sums[d] * inv_n;
  float ex2 = sums[D + d] * inv_n;
  float ms = gn_ms[d];
  float var = ex2 - 2.f * ms * mean * mean + ms * ms * mean * mean;
  float inv = 1.f / sqrtf(var + 1e-5f);
  float scale = gn_w[d] * inv;
  float shift = gn_b[d] - ms * mean * scale;
  scsh[d] = scale;
  scsh[D + d] = shift;
}

// ---------------- FFN GEMM1: t = gelu(hn @ W1 + b1), hn = h*scale+shift ----------------
__global__ __launch_bounds__(256) void ffn1(
    const float* __restrict__ h, const float* __restrict__ scsh,
    const ushort* __restrict__ W1t, const float* __restrict__ b1,
    ushort* __restrict__ tbf, int n) {
  int wv = threadIdx.x >> 6;
  int l = threadIdx.x & 63;
  int lr = l & 15, lg = l >> 4;
  int r0 = blockIdx.x * 64;
  int c0 = wv * 128;
  f32x4 acc[4][8];
#pragma unroll
  for (int m = 0; m < 4; ++m)
#pragma unroll
    for (int nn = 0; nn < 8; ++nn) acc[m][nn] = (f32x4)0.f;
#pragma unroll
  for (int kb = 0; kb < 4; ++kb) {
    int k0 = kb * 32 + lg * 8;
    float4 s0 = *reinterpret_cast<const float4*>(scsh + k0);
    float4 s1 = *reinterpret_cast<const float4*>(scsh + k0 + 4);
    float4 t0 = *reinterpret_cast<const float4*>(scsh + D + k0);
    float4 t1 = *reinterpret_cast<const float4*>(scsh + D + k0 + 4);
    bf16x8 a[4];
#pragma unroll
    for (int m = 0; m < 4; ++m) {
      int row = r0 + m * 16 + lr;
      row = min(row, n - 1);
      const float* p = h + (size_t)row * D + k0;
      float4 x0 = *reinterpret_cast<const float4*>(p);
      float4 x1 = *reinterpret_cast<const float4*>(p + 4);
      bf16x8 r;
      r[0] = (short)f2bf(x0.x * s0.x + t0.x);
      r[1] = (short)f2bf(x0.y * s0.y + t0.y);
      r[2] = (short)f2bf(x0.z * s0.z + t0.z);
      r[3] = (short)f2bf(x0.w * s0.w + t0.w);
      r[4] = (short)f2bf(x1.x * s1.x + t1.x);
      r[5] = (short)f2bf(x1.y * s1.y + t1.y);
      r[6] = (short)f2bf(x1.z * s1.z + t1.z);
      r[7] = (short)f2bf(x1.w * s1.w + t1.w);
      a[m] = r;
    }
    bf16x8 b[8];
#pragma unroll
    for (int nn = 0; nn < 8; ++nn)
      b[nn] = *reinterpret_cast<const bf16x8*>(W1t + (c0 + nn * 16 + lr) * D + k0);
#pragma unroll
    for (int m = 0; m < 4; ++m)
#pragma unroll
      for (int nn = 0; nn < 8; ++nn)
        acc[m][nn] = __builtin_amdgcn_mfma_f32_16x16x32_bf16(a[m], b[nn], acc[m][nn], 0, 0, 0);
  }
  const float inv_sqrt2 = 0.70710678118654752440f;
#pragma unroll
  for (int m = 0; m < 4; ++m)
#pragma unroll
    for (int nn = 0; nn < 8; ++nn) {
      int col = c0 + nn * 16 + lr;
      float bb = b1[col];
#pragma unroll
      for (int j = 0; j < 4; ++j) {
        int row = r0 + m * 16 + lg * 4 + j;
        if (row < n) {
          float val = acc[m][nn][j] + bb;
          val = 0.5f * val * (1.f + erff(val * inv_sqrt2));
          tbf[(size_t)row * FF + col] = f2bf(val);
        }
      }
    }
}

// ---------------- FFN GEMM2: out = hn + t @ W2 + b2 (in place on h/d_out) ----------------
__global__ __launch_bounds__(256) void ffn2(
    const ushort* __restrict__ tbf, const ushort* __restrict__ W2t,
    const float* __restrict__ b2, const float* __restrict__ scsh,
    float* __restrict__ h, int n) {
  int wv = threadIdx.x >> 6;
  int l = threadIdx.x & 63;
  int lr = l & 15, lg = l >> 4;
  int r0 = blockIdx.x * 64;
  f32x4 acc[4][2];
#pragma unroll
  for (int m = 0; m < 4; ++m)
#pragma unroll
    for (int nn = 0; nn < 2; ++nn) acc[m][nn] = (f32x4)0.f;
#pragma unroll 4
  for (int kb = 0; kb < 16; ++kb) {
    int k0 = kb * 32 + lg * 8;
    bf16x8 a[4];
#pragma unroll
    for (int m = 0; m < 4; ++m) {
      int row = r0 + m * 16 + lr;
      row = min(row, n - 1);
      a[m] = *reinterpret_cast<const bf16x8*>(tbf + (size_t)row * FF + k0);
    }
    bf16x8 b[2];
#pragma unroll
    for (int nn = 0; nn < 2; ++nn)
      b[nn] = *reinterpret_cast<const bf16x8*>(W2t + (wv * 32 + nn * 16 + lr) * FF + k0);
#pragma unroll
    for (int m = 0; m < 4; ++m)
#pragma unroll
      for (int nn = 0; nn < 2; ++nn)
        acc[m][nn] = __builtin_amdgcn_mfma_f32_16x16x32_bf16(a[m], b[nn], acc[m][nn], 0, 0, 0);
  }
#pragma unroll
  for (int m = 0; m < 4; ++m)
#pragma unroll
    for (int nn = 0; nn < 2; ++nn) {
      int col = wv * 32 + nn * 16 + lr;
      float bb = b2[col];
      float sc = scsh[col], sh = scsh[D + col];
#pragma unroll
      for (int j = 0; j < 4; ++j) {
        int row = r0 + m * 16 + lg * 4 + j;
        if (row < n) {
          size_t idx = (size_t)row * D + col;
          float hn = h[idx] * sc + sh;
          h[idx] = hn + acc[m][nn][j] + bb;
        }
      }
    }
}

extern "C" void kernel_launch(void* const* d_in, const int* in_sizes, int n_in,
                              void* d_out, int out_size, void* d_ws, size_t ws_size,
                              hipStream_t stream) {
  const float* x     = (const float*)d_in[0];
  const int*   ei    = (const int*)d_in[1];
  const float* attr  = (const float*)d_in[2];
  const float* Wq    = (const float*)d_in[3];
  const float* bq    = (const float*)d_in[4];
  const float* Wk    = (const float*)d_in[5];
  const float* bk    = (const float*)d_in[6];
  const float* Wv    = (const float*)d_in[7];
  const float* bv    = (const float*)d_in[8];
  const float* We    = (const float*)d_in[9];
  const float* Wskip = (const float*)d_in[10];
  const float* bskip = (const float*)d_in[11];
  const float* Wbeta = (const float*)d_in[12];
  const float* gn_w  = (const float*)d_in[13];
  const float* gn_b  = (const float*)d_in[14];
  const float* gn_ms = (const float*)d_in[15];
  const float* W1    = (const float*)d_in[16];
  const float* b1    = (const float*)d_in[17];
  const float* W2    = (const float*)d_in[18];
  const float* b2    = (const float*)d_in[19];

  const int n = in_sizes[0] / D;
  const int E = in_sizes[1] / 2;
  const int* src = ei;
  const int* dst = ei + E;
  const size_t ND = (size_t)n * D;

  // ---- workspace layout (16B-aligned segments) ----
  ushort* qb = (ushort*)d_ws;                 // ND bf16
  ushort* kb = qb + ND;                       // ND bf16
  ushort* vb = kb + ND;                       // ND bf16
  float* xr = (float*)(vb + ND);              // ND f32
  int* deg = (int*)(xr + ND);                 // n   (zeroed)
  int* cursor = deg + n;                      // n   (zeroed)
  float* sums = (float*)(cursor + n);         // 2D  (zeroed)
  int* off = (int*)(sums + 2 * D);            // n
  int* sorted = off + n;                      // E
  ushort* Wcat_t = (ushort*)(sorted + E);     // 4*D*D
  ushort* W1t = Wcat_t + 4 * D * D;           // D*FF
  ushort* W2t = W1t + D * FF;                 // FF*D
  float* bcat = (float*)(W2t + FF * D);       // 4D
  float* scsh = bcat + 4 * D;                 // 2D
  ushort* tbf = (ushort*)(scsh + 2 * D);      // N*FF bf16

  hipMemsetAsync(deg, 0, (2 * (size_t)n + 2 * D) * sizeof(int), stream);

  prep_weights<<<(4 * D * D + 255) / 256, 256, 0, stream>>>(
      Wq, Wk, Wv, Wskip, bq, bk, bv, bskip, W1, W2, Wcat_t, bcat, W1t, W2t);

  int gm = (n + 63) / 64;
  gemm_in<<<gm, 256, 0, stream>>>(x, Wcat_t, bcat, qb, kb, vb, xr, n);

  hist_kernel<<<(E + 255) / 256, 256, 0, stream>>>(dst, deg, E);
  scan_kernel<<<1, 1024, 0, stream>>>(deg, off, n);
  scatter_kernel<<<(E + 255) / 256, 256, 0, stream>>>(dst, off, cursor, sorted, E);

  node_attn<<<2048, 256, 0, stream>>>(src, sorted, off, deg, attr, We, qb, kb, vb, xr, x,
                                      Wbeta, (float*)d_out, sums, n);
  gn_stats<<<1, 128, 0, stream>>>(sums, gn_w, gn_b, gn_ms, scsh, 1.f / (float)n);

  ffn1<<<gm, 256, 0, stream>>>((const float*)d_out, scsh, W1t, b1, tbf, n);
  ffn2<<<gm, 256, 0, stream>>>(tbf, W2t, b2, scsh, (float*)d_out, n);
}

// Round 4
// 560.835 us; speedup vs baseline: 4.4902x; 1.2027x over previous
//
#include <hip/hip_runtime.h>
#include <math.h>

#define D 128
#define H 8
#define C 16
#define ED 10
#define FF 512
#define TPAD 520  // 512 + 8 bf16 pad: breaks power-of-2 LDS row stride

typedef __attribute__((ext_vector_type(4))) float f32x4;
typedef __attribute__((ext_vector_type(8))) short bf16x8;

__device__ __forceinline__ ushort f2bf(float f) {
  unsigned u = __float_as_uint(f);
  unsigned r = u + 0x7fffu + ((u >> 16) & 1u);
  return (ushort)(r >> 16);
}
__device__ __forceinline__ float bf2f(ushort u) {
  return __uint_as_float(((unsigned)u) << 16);
}

// ---------------- weight prep: transpose + cast to bf16 ----------------
__global__ void prep_weights(const float* __restrict__ Wq, const float* __restrict__ Wk,
                             const float* __restrict__ Wv, const float* __restrict__ Wskip,
                             const float* __restrict__ bq, const float* __restrict__ bk,
                             const float* __restrict__ bv, const float* __restrict__ bskip,
                             const float* __restrict__ W1, const float* __restrict__ W2,
                             ushort* __restrict__ Wcat_t, float* __restrict__ bcat,
                             ushort* __restrict__ W1t, ushort* __restrict__ W2t) {
  int t = blockIdx.x * blockDim.x + threadIdx.x;  // 0..65535
  if (t >= 4 * D * D) return;
  {
    int w = t >> 14, c = (t >> 7) & 127, kk = t & 127;
    const float* W = (w == 0) ? Wq : (w == 1) ? Wk : (w == 2) ? Wv : Wskip;
    Wcat_t[t] = f2bf(W[kk * D + c]);
  }
  {
    int f = t >> 7, kk = t & 127;
    W1t[t] = f2bf(W1[kk * FF + f]);
  }
  {
    int c = t >> 9, f = t & 511;
    W2t[t] = f2bf(W2[f * D + c]);
  }
  if (t < 4 * D) {
    int w = t >> 7;
    const float* b = (w == 0) ? bq : (w == 1) ? bk : (w == 2) ? bv : bskip;
    bcat[t] = b[t & 127];
  }
}

__device__ __forceinline__ bf16x8 load_a_f32(const float* p) {
  float4 x0 = *reinterpret_cast<const float4*>(p);
  float4 x1 = *reinterpret_cast<const float4*>(p + 4);
  bf16x8 r;
  r[0] = (short)f2bf(x0.x); r[1] = (short)f2bf(x0.y);
  r[2] = (short)f2bf(x0.z); r[3] = (short)f2bf(x0.w);
  r[4] = (short)f2bf(x1.x); r[5] = (short)f2bf(x1.y);
  r[6] = (short)f2bf(x1.z); r[7] = (short)f2bf(x1.w);
  return r;
}

// ---------------- fused q/k/v/xr GEMM: [N,128] @ 4x[128,128] ----------------
__global__ __launch_bounds__(256) void gemm_in(
    const float* __restrict__ x, const ushort* __restrict__ Wcat_t,
    const float* __restrict__ bcat, ushort* __restrict__ qb, ushort* __restrict__ kb,
    ushort* __restrict__ vb, float* __restrict__ xr, int n) {
  int wv = threadIdx.x >> 6;
  int l = threadIdx.x & 63;
  int lr = l & 15, lg = l >> 4;
  int r0 = blockIdx.x * 64;
  const ushort* Wt = Wcat_t + wv * D * D;
  f32x4 acc[4][8];
#pragma unroll
  for (int m = 0; m < 4; ++m)
#pragma unroll
    for (int nn = 0; nn < 8; ++nn) acc[m][nn] = (f32x4)0.f;
#pragma unroll
  for (int kb2 = 0; kb2 < 4; ++kb2) {
    int k0 = kb2 * 32 + lg * 8;
    bf16x8 a[4];
#pragma unroll
    for (int m = 0; m < 4; ++m) {
      int row = r0 + m * 16 + lr;
      row = min(row, n - 1);
      a[m] = load_a_f32(x + (size_t)row * D + k0);
    }
    bf16x8 b[8];
#pragma unroll
    for (int nn = 0; nn < 8; ++nn)
      b[nn] = *reinterpret_cast<const bf16x8*>(Wt + (nn * 16 + lr) * D + k0);
#pragma unroll
    for (int m = 0; m < 4; ++m)
#pragma unroll
      for (int nn = 0; nn < 8; ++nn)
        acc[m][nn] = __builtin_amdgcn_mfma_f32_16x16x32_bf16(a[m], b[nn], acc[m][nn], 0, 0, 0);
  }
  ushort* ub = (wv == 0) ? qb : (wv == 1) ? kb : vb;
#pragma unroll
  for (int m = 0; m < 4; ++m)
#pragma unroll
    for (int nn = 0; nn < 8; ++nn) {
      int col = nn * 16 + lr;
      float bb = bcat[wv * D + col];
#pragma unroll
      for (int j = 0; j < 4; ++j) {
        int row = r0 + m * 16 + lg * 4 + j;
        if (row < n) {
          float val = acc[m][nn][j] + bb;
          if (wv < 3) ub[(size_t)row * D + col] = f2bf(val);
          else xr[(size_t)row * D + col] = val;
        }
      }
    }
}

// ---------------- CSR build ----------------
__global__ void hist_kernel(const int* __restrict__ dst, int* __restrict__ deg, int E) {
  int t = blockIdx.x * blockDim.x + threadIdx.x;
  if (t < E) atomicAdd(&deg[dst[t]], 1);
}

__global__ __launch_bounds__(1024) void scan_kernel(const int* __restrict__ deg,
                                                    int* __restrict__ off, int n) {
  __shared__ int part[1024];
  int t = threadIdx.x;
  int chunk = (n + 1023) / 1024;
  int lo = t * chunk, hi = min(lo + chunk, n);
  int s = 0;
  for (int i = lo; i < hi; ++i) s += deg[i];
  part[t] = s;
  __syncthreads();
  for (int dd = 1; dd < 1024; dd <<= 1) {
    int v = (t >= dd) ? part[t - dd] : 0;
    __syncthreads();
    part[t] += v;
    __syncthreads();
  }
  int excl = (t == 0) ? 0 : part[t - 1];
  for (int i = lo; i < hi; ++i) {
    off[i] = excl;
    excl += deg[i];
  }
}

__global__ void scatter_kernel(const int* __restrict__ dst, const int* __restrict__ off,
                               int* __restrict__ cursor, int* __restrict__ sorted, int E) {
  int t = blockIdx.x * blockDim.x + threadIdx.x;
  if (t >= E) return;
  int dd = dst[t];
  int p = atomicAdd(&cursor[dd], 1);
  sorted[off[dd] + p] = t;
}

// ---------------- fused node-centric attention (MLP-pipelined) ----------------
// one wave per node; lane l owns features d0=2l, d1=2l+1 (head = l>>3).
__global__ __launch_bounds__(256) void node_attn(
    const int* __restrict__ src, const int* __restrict__ sorted,
    const int* __restrict__ off, const int* __restrict__ deg,
    const float* __restrict__ attr, const float* __restrict__ We,
    const ushort* __restrict__ qb, const ushort* __restrict__ kb,
    const ushort* __restrict__ vb, const float* __restrict__ xr,
    const float* __restrict__ x, const float* __restrict__ Wbeta,
    float* __restrict__ h, float* __restrict__ sums, int n) {
  __shared__ float2 WeS2[ED * 64];  // WeS2[j*64+l] = (We[j][2l], We[j][2l+1])
  __shared__ float rs_h[4 * D], rs_h2[4 * D];
  for (int i = threadIdx.x; i < ED * 64; i += 256) {
    int j = i >> 6, ll = i & 63;
    WeS2[i] = make_float2(We[j * D + 2 * ll], We[j * D + 2 * ll + 1]);
  }
  __syncthreads();
  int wid = threadIdx.x >> 6;
  int l = threadIdx.x & 63;
  int d0 = 2 * l;
  float2 wb0 = *reinterpret_cast<const float2*>(Wbeta + d0);
  float2 wb1 = *reinterpret_cast<const float2*>(Wbeta + D + d0);
  float2 wb2 = *reinterpret_cast<const float2*>(Wbeta + 2 * D + d0);
  float s_h0 = 0.f, s_h20 = 0.f, s_h1 = 0.f, s_h21 = 0.f;
  for (int node = blockIdx.x * 4 + wid; node < n; node += gridDim.x * 4) {
    const ushort2 qu = *reinterpret_cast<const ushort2*>(qb + (size_t)node * D + d0);
    float q0 = bf2f(qu.x), q1 = bf2f(qu.y);
    int o0 = off[node], dg = deg[node];
    float m = -1e30f, den = 0.f, acc0 = 0.f, acc1 = 0.f;
    for (int chunk = 0; chunk < dg; chunk += 64) {
      int cnt = min(64, dg - chunk);
      // cooperative, coalesced staging of edge ids + src ids for this chunk
      int e_l = 0, s_l = 0;
      if (chunk + l < dg) {
        e_l = sorted[o0 + chunk + l];
        s_l = src[e_l];
      }
      // 1-ahead prefetch pipeline
      int s_p = __shfl(s_l, 0), e_p = __shfl(e_l, 0);
      ushort2 ku_n = *reinterpret_cast<const ushort2*>(kb + (size_t)s_p * D + d0);
      ushort2 vu_n = *reinterpret_cast<const ushort2*>(vb + (size_t)s_p * D + d0);
      const float2* ap = reinterpret_cast<const float2*>(attr + (size_t)e_p * ED);
      float2 a0n = ap[0], a1n = ap[1], a2n = ap[2], a3n = ap[3], a4n = ap[4];
      for (int i = 0; i < cnt; ++i) {
        ushort2 ku = ku_n, vu = vu_n;
        float2 a0 = a0n, a1 = a1n, a2 = a2n, a3 = a3n, a4 = a4n;
        if (i + 1 < cnt) {
          int s2 = __shfl(s_l, i + 1), e2 = __shfl(e_l, i + 1);
          ku_n = *reinterpret_cast<const ushort2*>(kb + (size_t)s2 * D + d0);
          vu_n = *reinterpret_cast<const ushort2*>(vb + (size_t)s2 * D + d0);
          const float2* ap2 = reinterpret_cast<const float2*>(attr + (size_t)e2 * ED);
          a0n = ap2[0]; a1n = ap2[1]; a2n = ap2[2]; a3n = ap2[3]; a4n = ap2[4];
        }
        float ec0, ec1;
        {
          float2 w;
          w = WeS2[0 * 64 + l]; ec0 = a0.x * w.x;           ec1 = a0.x * w.y;
          w = WeS2[1 * 64 + l]; ec0 = fmaf(a0.y, w.x, ec0); ec1 = fmaf(a0.y, w.y, ec1);
          w = WeS2[2 * 64 + l]; ec0 = fmaf(a1.x, w.x, ec0); ec1 = fmaf(a1.x, w.y, ec1);
          w = WeS2[3 * 64 + l]; ec0 = fmaf(a1.y, w.x, ec0); ec1 = fmaf(a1.y, w.y, ec1);
          w = WeS2[4 * 64 + l]; ec0 = fmaf(a2.x, w.x, ec0); ec1 = fmaf(a2.x, w.y, ec1);
          w = WeS2[5 * 64 + l]; ec0 = fmaf(a2.y, w.x, ec0); ec1 = fmaf(a2.y, w.y, ec1);
          w = WeS2[6 * 64 + l]; ec0 = fmaf(a3.x, w.x, ec0); ec1 = fmaf(a3.x, w.y, ec1);
          w = WeS2[7 * 64 + l]; ec0 = fmaf(a3.y, w.x, ec0); ec1 = fmaf(a3.y, w.y, ec1);
          w = WeS2[8 * 64 + l]; ec0 = fmaf(a4.x, w.x, ec0); ec1 = fmaf(a4.x, w.y, ec1);
          w = WeS2[9 * 64 + l]; ec0 = fmaf(a4.y, w.x, ec0); ec1 = fmaf(a4.y, w.y, ec1);
        }
        float kk0 = bf2f(ku.x) + ec0, kk1 = bf2f(ku.y) + ec1;
        float vv0 = bf2f(vu.x) + ec0, vv1 = bf2f(vu.y) + ec1;
        float p = q0 * kk0 + q1 * kk1;
        p += __shfl_xor(p, 1, 8);
        p += __shfl_xor(p, 2, 8);
        p += __shfl_xor(p, 4, 8);
        float a = p * 0.25f;
        float mn = fmaxf(m, a);
        float sc = __expf(m - mn);
        float ex = __expf(a - mn);
        den = den * sc + ex;
        acc0 = acc0 * sc + ex * vv0;
        acc1 = acc1 * sc + ex * vv1;
        m = mn;
      }
    }
    float inv = 1.f / (den + 1e-16f);
    float oo0 = acc0 * inv, oo1 = acc1 * inv;
    float2 xr2 = *reinterpret_cast<const float2*>(xr + (size_t)node * D + d0);
    float2 x2 = *reinterpret_cast<const float2*>(x + (size_t)node * D + d0);
    float pb = oo0 * wb0.x + xr2.x * wb1.x + (oo0 - xr2.x) * wb2.x
             + oo1 * wb0.y + xr2.y * wb1.y + (oo1 - xr2.y) * wb2.y;
#pragma unroll
    for (int msk = 1; msk < 64; msk <<= 1) pb += __shfl_xor(pb, msk, 64);
    float beta = 1.f / (1.f + __expf(-pb));
    float h0 = x2.x + beta * xr2.x + (1.f - beta) * oo0;
    float h1 = x2.y + beta * xr2.y + (1.f - beta) * oo1;
    *reinterpret_cast<float2*>(h + (size_t)node * D + d0) = make_float2(h0, h1);
    s_h0 += h0; s_h20 += h0 * h0;
    s_h1 += h1; s_h21 += h1 * h1;
  }
  rs_h[wid * D + d0] = s_h0;   rs_h[wid * D + d0 + 1] = s_h1;
  rs_h2[wid * D + d0] = s_h20; rs_h2[wid * D + d0 + 1] = s_h21;
  __syncthreads();
  if (threadIdx.x < D) {
    int d = threadIdx.x;
    float sh = rs_h[d] + rs_h[D + d] + rs_h[2 * D + d] + rs_h[3 * D + d];
    float sh2 = rs_h2[d] + rs_h2[D + d] + rs_h2[2 * D + d] + rs_h2[3 * D + d];
    atomicAdd(&sums[d], sh);
    atomicAdd(&sums[D + d], sh2);
  }
}

__global__ void gn_stats(const float* __restrict__ sums, const float* __restrict__ gn_w,
                         const float* __restrict__ gn_b, const float* __restrict__ gn_ms,
                         float* __restrict__ scsh, float inv_n) {
  int d = threadIdx.x;
  float mean = sums[d] * inv_n;
  float ex2 = sums[D + d] * inv_n;
  float ms = gn_ms[d];
  float var = ex2 - 2.f * ms * mean * mean + ms * ms * mean * mean;
  float inv = 1.f / sqrtf(var + 1e-5f);
  float scale = gn_w[d] * inv;
  float shift = gn_b[d] - ms * mean * scale;
  scsh[d] = scale;
  scsh[D + d] = shift;
}

// ---------------- fused FFN: out = hn + gelu(hn@W1+b1)@W2 + b2, hn = h*sc+sh ------------
// t tile (64x512 bf16) staged in LDS, row stride padded to 520.
__global__ __launch_bounds__(256) void ffn_fused(
    const float* __restrict__ h, const float* __restrict__ scsh,
    const ushort* __restrict__ W1t, const float* __restrict__ b1,
    const ushort* __restrict__ W2t, const float* __restrict__ b2,
    float* __restrict__ out, int n) {
  __shared__ ushort tt[64 * TPAD];  // 66560 B
  int wv = threadIdx.x >> 6;
  int l = threadIdx.x & 63;
  int lr = l & 15, lg = l >> 4;
  int r0 = blockIdx.x * 64;
  int c0 = wv * 128;
  // ---- GEMM1: t = gelu(hn @ W1 + b1), this wave: cols [c0, c0+128) ----
  {
    f32x4 acc[4][8];
#pragma unroll
    for (int m = 0; m < 4; ++m)
#pragma unroll
      for (int nn = 0; nn < 8; ++nn) acc[m][nn] = (f32x4)0.f;
#pragma unroll
    for (int kb = 0; kb < 4; ++kb) {
      int k0 = kb * 32 + lg * 8;
      float4 s0 = *reinterpret_cast<const float4*>(scsh + k0);
      float4 s1 = *reinterpret_cast<const float4*>(scsh + k0 + 4);
      float4 t0 = *reinterpret_cast<const float4*>(scsh + D + k0);
      float4 t1 = *reinterpret_cast<const float4*>(scsh + D + k0 + 4);
      bf16x8 a[4];
#pragma unroll
      for (int m = 0; m < 4; ++m) {
        int row = r0 + m * 16 + lr;
        row = min(row, n - 1);
        const float* p = h + (size_t)row * D + k0;
        float4 x0 = *reinterpret_cast<const float4*>(p);
        float4 x1 = *reinterpret_cast<const float4*>(p + 4);
        bf16x8 r;
        r[0] = (short)f2bf(x0.x * s0.x + t0.x);
        r[1] = (short)f2bf(x0.y * s0.y + t0.y);
        r[2] = (short)f2bf(x0.z * s0.z + t0.z);
        r[3] = (short)f2bf(x0.w * s0.w + t0.w);
        r[4] = (short)f2bf(x1.x * s1.x + t1.x);
        r[5] = (short)f2bf(x1.y * s1.y + t1.y);
        r[6] = (short)f2bf(x1.z * s1.z + t1.z);
        r[7] = (short)f2bf(x1.w * s1.w + t1.w);
        a[m] = r;
      }
      bf16x8 b[8];
#pragma unroll
      for (int nn = 0; nn < 8; ++nn)
        b[nn] = *reinterpret_cast<const bf16x8*>(W1t + (c0 + nn * 16 + lr) * D + k0);
#pragma unroll
      for (int m = 0; m < 4; ++m)
#pragma unroll
        for (int nn = 0; nn < 8; ++nn)
          acc[m][nn] = __builtin_amdgcn_mfma_f32_16x16x32_bf16(a[m], b[nn], acc[m][nn], 0, 0, 0);
    }
    const float inv_sqrt2 = 0.70710678118654752440f;
#pragma unroll
    for (int m = 0; m < 4; ++m)
#pragma unroll
      for (int nn = 0; nn < 8; ++nn) {
        int col = c0 + nn * 16 + lr;
        float bb = b1[col];
#pragma unroll
        for (int j = 0; j < 4; ++j) {
          int rowl = m * 16 + lg * 4 + j;
          float val = acc[m][nn][j] + bb;
          val = 0.5f * val * (1.f + erff(val * inv_sqrt2));
          tt[rowl * TPAD + col] = f2bf(val);
        }
      }
  }
  __syncthreads();
  // ---- GEMM2: out = hn + t @ W2 + b2, this wave: cols [wv*32, wv*32+32) ----
  {
    f32x4 acc[4][2];
#pragma unroll
    for (int m = 0; m < 4; ++m)
#pragma unroll
      for (int nn = 0; nn < 2; ++nn) acc[m][nn] = (f32x4)0.f;
#pragma unroll 4
    for (int kb = 0; kb < 16; ++kb) {
      int k0 = kb * 32 + lg * 8;
      bf16x8 a[4];
#pragma unroll
      for (int m = 0; m < 4; ++m)
        a[m] = *reinterpret_cast<const bf16x8*>(tt + (m * 16 + lr) * TPAD + k0);
      bf16x8 b[2];
#pragma unroll
      for (int nn = 0; nn < 2; ++nn)
        b[nn] = *reinterpret_cast<const bf16x8*>(W2t + (wv * 32 + nn * 16 + lr) * FF + k0);
#pragma unroll
      for (int m = 0; m < 4; ++m)
#pragma unroll
        for (int nn = 0; nn < 2; ++nn)
          acc[m][nn] = __builtin_amdgcn_mfma_f32_16x16x32_bf16(a[m], b[nn], acc[m][nn], 0, 0, 0);
    }
#pragma unroll
    for (int m = 0; m < 4; ++m)
#pragma unroll
      for (int nn = 0; nn < 2; ++nn) {
        int col = wv * 32 + nn * 16 + lr;
        float bb = b2[col];
        float sc = scsh[col], sh = scsh[D + col];
#pragma unroll
        for (int j = 0; j < 4; ++j) {
          int row = r0 + m * 16 + lg * 4 + j;
          if (row < n) {
            size_t idx = (size_t)row * D + col;
            float hn = h[idx] * sc + sh;
            out[idx] = hn + acc[m][nn][j] + bb;
          }
        }
      }
  }
}

extern "C" void kernel_launch(void* const* d_in, const int* in_sizes, int n_in,
                              void* d_out, int out_size, void* d_ws, size_t ws_size,
                              hipStream_t stream) {
  const float* x     = (const float*)d_in[0];
  const int*   ei    = (const int*)d_in[1];
  const float* attr  = (const float*)d_in[2];
  const float* Wq    = (const float*)d_in[3];
  const float* bq    = (const float*)d_in[4];
  const float* Wk    = (const float*)d_in[5];
  const float* bk    = (const float*)d_in[6];
  const float* Wv    = (const float*)d_in[7];
  const float* bv    = (const float*)d_in[8];
  const float* We    = (const float*)d_in[9];
  const float* Wskip = (const float*)d_in[10];
  const float* bskip = (const float*)d_in[11];
  const float* Wbeta = (const float*)d_in[12];
  const float* gn_w  = (const float*)d_in[13];
  const float* gn_b  = (const float*)d_in[14];
  const float* gn_ms = (const float*)d_in[15];
  const float* W1    = (const float*)d_in[16];
  const float* b1    = (const float*)d_in[17];
  const float* W2    = (const float*)d_in[18];
  const float* b2    = (const float*)d_in[19];

  const int n = in_sizes[0] / D;
  const int E = in_sizes[1] / 2;
  const int* src = ei;
  const int* dst = ei + E;
  const size_t ND = (size_t)n * D;

  // ---- workspace layout ----
  ushort* qb = (ushort*)d_ws;                 // ND bf16
  ushort* kb = qb + ND;                       // ND bf16
  ushort* vb = kb + ND;                       // ND bf16
  float* xr = (float*)(vb + ND);              // ND f32
  int* deg = (int*)(xr + ND);                 // n   (zeroed)
  int* cursor = deg + n;                      // n   (zeroed)
  float* sums = (float*)(cursor + n);         // 2D  (zeroed)
  int* off = (int*)(sums + 2 * D);            // n
  int* sorted = off + n;                      // E
  ushort* Wcat_t = (ushort*)(sorted + E);     // 4*D*D
  ushort* W1t = Wcat_t + 4 * D * D;           // D*FF
  ushort* W2t = W1t + D * FF;                 // FF*D
  float* bcat = (float*)(W2t + FF * D);       // 4D
  float* scsh = bcat + 4 * D;                 // 2D

  hipMemsetAsync(deg, 0, (2 * (size_t)n + 2 * D) * sizeof(int), stream);

  prep_weights<<<(4 * D * D + 255) / 256, 256, 0, stream>>>(
      Wq, Wk, Wv, Wskip, bq, bk, bv, bskip, W1, W2, Wcat_t, bcat, W1t, W2t);

  int gm = (n + 63) / 64;
  gemm_in<<<gm, 256, 0, stream>>>(x, Wcat_t, bcat, qb, kb, vb, xr, n);

  hist_kernel<<<(E + 255) / 256, 256, 0, stream>>>(dst, deg, E);
  scan_kernel<<<1, 1024, 0, stream>>>(deg, off, n);
  scatter_kernel<<<(E + 255) / 256, 256, 0, stream>>>(dst, off, cursor, sorted, E);

  node_attn<<<2048, 256, 0, stream>>>(src, sorted, off, deg, attr, We, qb, kb, vb, xr, x,
                                      Wbeta, (float*)d_out, sums, n);
  gn_stats<<<1, 128, 0, stream>>>(sums, gn_w, gn_b, gn_ms, scsh, 1.f / (float)n);

  ffn_fused<<<gm, 256, 0, stream>>>((const float*)d_out, scsh, W1t, b1, W2t, b2,
                                    (float*)d_out, n);
}

// Round 6
// 521.471 us; speedup vs baseline: 4.8292x; 1.0755x over previous
//
#include <hip/hip_runtime.h>
#include <hip/hip_fp16.h>
#include <math.h>

#define D 128
#define ED 10
#define FF 512
#define TPAD 520  // bf16 elements per LDS row (512 + 8 pad)

typedef __attribute__((ext_vector_type(4))) float f32x4;
typedef __attribute__((ext_vector_type(8))) short bf16x8;
using h2 = decltype(__builtin_amdgcn_cvt_pkrtz(0.f, 0.f));  // __fp16 ext_vector(2)

__device__ __forceinline__ ushort f2bf(float f) {
  unsigned u = __float_as_uint(f);
  unsigned r = u + 0x7fffu + ((u >> 16) & 1u);
  return (ushort)(r >> 16);
}
__device__ __forceinline__ float bf2f(ushort u) {
  return __uint_as_float(((unsigned)u) << 16);
}

// ---------------- kernel 1: weight prep (blocks 0..255) + degree histogram ----------
__global__ void prep_hist(const float* __restrict__ Wq, const float* __restrict__ Wk,
                          const float* __restrict__ Wv, const float* __restrict__ Wskip,
                          const float* __restrict__ bq, const float* __restrict__ bk,
                          const float* __restrict__ bv, const float* __restrict__ bskip,
                          const float* __restrict__ W1, const float* __restrict__ W2,
                          const int* __restrict__ dst, int* __restrict__ deg, int E,
                          ushort* __restrict__ Wcat_t, float* __restrict__ bcat,
                          ushort* __restrict__ W1t, ushort* __restrict__ W2t) {
  int b = blockIdx.x;
  if (b >= 256) {
    int t = (b - 256) * 256 + threadIdx.x;
    if (t < E) atomicAdd(&deg[dst[t]], 1);
    return;
  }
  int t = b * 256 + threadIdx.x;  // 0..65535
  {
    int w = t >> 14, c = (t >> 7) & 127, kk = t & 127;
    const float* W = (w == 0) ? Wq : (w == 1) ? Wk : (w == 2) ? Wv : Wskip;
    Wcat_t[t] = f2bf(W[kk * D + c]);
  }
  {
    int f = t >> 7, kk = t & 127;
    W1t[t] = f2bf(W1[kk * FF + f]);
  }
  {
    int c = t >> 9, f = t & 511;
    W2t[t] = f2bf(W2[f * D + c]);
  }
  if (t < 4 * D) {
    int w = t >> 7;
    const float* bb = (w == 0) ? bq : (w == 1) ? bk : (w == 2) ? bv : bskip;
    bcat[t] = bb[t & 127];
  }
}

// ---------------- kernel 2: exclusive scan of deg -> off[0..n] ----------------
__global__ __launch_bounds__(1024) void scan_kernel(const int* __restrict__ deg,
                                                    int* __restrict__ off, int n) {
  __shared__ int part[1024];
  int t = threadIdx.x;
  int chunk = (n + 1023) / 1024;
  int lo = t * chunk, hi = min(lo + chunk, n);
  int s = 0;
  for (int i = lo; i < hi; ++i) s += deg[i];
  part[t] = s;
  __syncthreads();
  for (int dd = 1; dd < 1024; dd <<= 1) {
    int v = (t >= dd) ? part[t - dd] : 0;
    __syncthreads();
    part[t] += v;
    __syncthreads();
  }
  int excl = (t == 0) ? 0 : part[t - 1];
  for (int i = lo; i < hi; ++i) {
    off[i] = excl;
    excl += deg[i];
  }
  if (t == 1023) off[n] = part[1023];
}

__device__ __forceinline__ bf16x8 load_a_f32(const float* p) {
  float4 x0 = *reinterpret_cast<const float4*>(p);
  float4 x1 = *reinterpret_cast<const float4*>(p + 4);
  bf16x8 r;
  r[0] = (short)f2bf(x0.x); r[1] = (short)f2bf(x0.y);
  r[2] = (short)f2bf(x0.z); r[3] = (short)f2bf(x0.w);
  r[4] = (short)f2bf(x1.x); r[5] = (short)f2bf(x1.y);
  r[6] = (short)f2bf(x1.z); r[7] = (short)f2bf(x1.w);
  return r;
}

// ---------------- kernel 3: fused q/kv/xr GEMM (blocks < gm) + CSR scatter ----------
// gemm: [N,128] @ 4x[128,128]; wave 0->q (bf16), 1->k, 2->v (interleaved kvb), 3->xr f32
__global__ __launch_bounds__(256) void gemm_scatter(
    const float* __restrict__ x, const ushort* __restrict__ Wcat_t,
    const float* __restrict__ bcat, ushort* __restrict__ qb, ushort* __restrict__ kvb,
    float* __restrict__ xr, int n, int gm,
    const int* __restrict__ dst, const int* __restrict__ off, int* __restrict__ cursor,
    int* __restrict__ sorted, int E) {
  if ((int)blockIdx.x >= gm) {
    int t = ((int)blockIdx.x - gm) * 256 + threadIdx.x;
    if (t < E) {
      int dd = dst[t];
      int p = atomicAdd(&cursor[dd], 1);
      sorted[off[dd] + p] = t;
    }
    return;
  }
  int wv = threadIdx.x >> 6;
  int l = threadIdx.x & 63;
  int lr = l & 15, lg = l >> 4;
  int r0 = blockIdx.x * 64;
  const ushort* Wt = Wcat_t + wv * D * D;
  f32x4 acc[4][8];
#pragma unroll
  for (int m = 0; m < 4; ++m)
#pragma unroll
    for (int nn = 0; nn < 8; ++nn) acc[m][nn] = (f32x4)0.f;
#pragma unroll
  for (int kb2 = 0; kb2 < 4; ++kb2) {
    int k0 = kb2 * 32 + lg * 8;
    bf16x8 a[4];
#pragma unroll
    for (int m = 0; m < 4; ++m) {
      int row = r0 + m * 16 + lr;
      row = min(row, n - 1);
      a[m] = load_a_f32(x + (size_t)row * D + k0);
    }
    bf16x8 b[8];
#pragma unroll
    for (int nn = 0; nn < 8; ++nn)
      b[nn] = *reinterpret_cast<const bf16x8*>(Wt + (nn * 16 + lr) * D + k0);
#pragma unroll
    for (int m = 0; m < 4; ++m)
#pragma unroll
      for (int nn = 0; nn < 8; ++nn)
        acc[m][nn] = __builtin_amdgcn_mfma_f32_16x16x32_bf16(a[m], b[nn], acc[m][nn], 0, 0, 0);
  }
#pragma unroll
  for (int m = 0; m < 4; ++m)
#pragma unroll
    for (int nn = 0; nn < 8; ++nn) {
      int col = nn * 16 + lr;
      float bb = bcat[wv * D + col];
#pragma unroll
      for (int j = 0; j < 4; ++j) {
        int row = r0 + m * 16 + lg * 4 + j;
        if (row < n) {
          float val = acc[m][nn][j] + bb;
          if (wv == 0) qb[(size_t)row * D + col] = f2bf(val);
          else if (wv == 1) kvb[((size_t)row * 64 + (col >> 1)) * 4 + (col & 1)] = f2bf(val);
          else if (wv == 2) kvb[((size_t)row * 64 + (col >> 1)) * 4 + 2 + (col & 1)] = f2bf(val);
          else xr[(size_t)row * D + col] = val;
        }
      }
    }
}

// ---------------- kernel 4: node-centric attention + beta gate + residual + GN sums ----
// one wave per node; lane l owns features d0=2l, d0+1 (head = l>>3).
__global__ __launch_bounds__(256) void node_attn(
    const int* __restrict__ src, const int* __restrict__ sorted,
    const int* __restrict__ off, const float* __restrict__ attr,
    const float* __restrict__ We, const ushort* __restrict__ qb,
    const ushort* __restrict__ kvb, const float* __restrict__ xr,
    const float* __restrict__ x, const float* __restrict__ Wbeta,
    float* __restrict__ h, float* __restrict__ sums, int n) {
  __shared__ h2 attrS[4][64][5];  // per-wave staged edge attrs (half2), 5.1 KB
  __shared__ float rs_h[4 * D], rs_h2[4 * D];
  int wid = threadIdx.x >> 6;
  int l = threadIdx.x & 63;
  int d0 = 2 * l;
  // hoist We columns d0, d0+1 into packed-half registers (K-pairs)
  h2 wA[5], wB[5];
#pragma unroll
  for (int t = 0; t < 5; ++t) {
    wA[t] = __builtin_amdgcn_cvt_pkrtz(We[(2 * t) * D + d0], We[(2 * t + 1) * D + d0]);
    wB[t] = __builtin_amdgcn_cvt_pkrtz(We[(2 * t) * D + d0 + 1], We[(2 * t + 1) * D + d0 + 1]);
  }
  float2 wb0 = *reinterpret_cast<const float2*>(Wbeta + d0);
  float2 wb1 = *reinterpret_cast<const float2*>(Wbeta + D + d0);
  float2 wb2 = *reinterpret_cast<const float2*>(Wbeta + 2 * D + d0);
  float s_h0 = 0.f, s_h20 = 0.f, s_h1 = 0.f, s_h21 = 0.f;
  for (int node = blockIdx.x * 4 + wid; node < n; node += gridDim.x * 4) {
    const ushort2 qu = *reinterpret_cast<const ushort2*>(qb + (size_t)node * D + d0);
    float q0 = bf2f(qu.x) * 0.25f, q1 = bf2f(qu.y) * 0.25f;  // fold 1/sqrt(C)
    int o0 = off[node], dg = off[node + 1] - o0;
    float m = -1e30f, den = 0.f, acc0 = 0.f, acc1 = 0.f;
    for (int chunk = 0; chunk < dg; chunk += 64) {
      int cnt = min(64, dg - chunk);
      // cooperative staging: edge ids, src ids, attrs (as half2) for 64 edges
      int s_l = 0;
      {
        int e_l = 0;
        if (chunk + l < dg) {
          e_l = sorted[o0 + chunk + l];
          s_l = src[e_l];
        }
        const float2* ap = reinterpret_cast<const float2*>(attr + (size_t)e_l * ED);
#pragma unroll
        for (int j = 0; j < 5; ++j) {
          float2 av = ap[j];
          attrS[wid][l][j] = __builtin_amdgcn_cvt_pkrtz(av.x, av.y);
        }
      }
      int s_nx = __shfl(s_l, 0);
      ushort4 kv_n = *reinterpret_cast<const ushort4*>(kvb + ((size_t)s_nx * 64 + l) * 4);
      for (int i = 0; i < cnt; ++i) {
        ushort4 kv = kv_n;
        if (i + 1 < cnt) {
          int s2 = __shfl(s_l, i + 1);
          kv_n = *reinterpret_cast<const ushort4*>(kvb + ((size_t)s2 * 64 + l) * 4);
        }
        h2 a0 = attrS[wid][i][0], a1 = attrS[wid][i][1], a2 = attrS[wid][i][2],
           a3 = attrS[wid][i][3], a4 = attrS[wid][i][4];
        float ec0 = __builtin_amdgcn_fdot2(a0, wA[0], 0.f, false);
        ec0 = __builtin_amdgcn_fdot2(a1, wA[1], ec0, false);
        ec0 = __builtin_amdgcn_fdot2(a2, wA[2], ec0, false);
        ec0 = __builtin_amdgcn_fdot2(a3, wA[3], ec0, false);
        ec0 = __builtin_amdgcn_fdot2(a4, wA[4], ec0, false);
        float ec1 = __builtin_amdgcn_fdot2(a0, wB[0], 0.f, false);
        ec1 = __builtin_amdgcn_fdot2(a1, wB[1], ec1, false);
        ec1 = __builtin_amdgcn_fdot2(a2, wB[2], ec1, false);
        ec1 = __builtin_amdgcn_fdot2(a3, wB[3], ec1, false);
        ec1 = __builtin_amdgcn_fdot2(a4, wB[4], ec1, false);
        float kk0 = bf2f(kv.x) + ec0, kk1 = bf2f(kv.y) + ec1;
        float vv0 = bf2f(kv.z) + ec0, vv1 = bf2f(kv.w) + ec1;
        float p = fmaf(q0, kk0, q1 * kk1);
        p += __shfl_xor(p, 1, 8);
        p += __shfl_xor(p, 2, 8);
        p += __shfl_xor(p, 4, 8);
        // defer-max online softmax (rescale only when max grows past threshold 8)
        if (__any(p > m + 8.f)) {
          float mn = fmaxf(m, p);
          float sc = __expf(m - mn);
          den *= sc; acc0 *= sc; acc1 *= sc;
          m = mn;
        }
        float ex = __expf(p - m);
        den += ex;
        acc0 = fmaf(ex, vv0, acc0);
        acc1 = fmaf(ex, vv1, acc1);
      }
    }
    float inv = 1.f / (den + 1e-16f);
    float oo0 = acc0 * inv, oo1 = acc1 * inv;
    float2 xr2 = *reinterpret_cast<const float2*>(xr + (size_t)node * D + d0);
    float2 x2 = *reinterpret_cast<const float2*>(x + (size_t)node * D + d0);
    float pb = oo0 * wb0.x + xr2.x * wb1.x + (oo0 - xr2.x) * wb2.x
             + oo1 * wb0.y + xr2.y * wb1.y + (oo1 - xr2.y) * wb2.y;
#pragma unroll
    for (int msk = 1; msk < 64; msk <<= 1) pb += __shfl_xor(pb, msk, 64);
    float beta = 1.f / (1.f + __expf(-pb));
    float h0 = x2.x + beta * xr2.x + (1.f - beta) * oo0;
    float h1 = x2.y + beta * xr2.y + (1.f - beta) * oo1;
    *reinterpret_cast<float2*>(h + (size_t)node * D + d0) = make_float2(h0, h1);
    s_h0 += h0; s_h20 += h0 * h0;
    s_h1 += h1; s_h21 += h1 * h1;
  }
  rs_h[wid * D + d0] = s_h0;   rs_h[wid * D + d0 + 1] = s_h1;
  rs_h2[wid * D + d0] = s_h20; rs_h2[wid * D + d0 + 1] = s_h21;
  __syncthreads();
  if (threadIdx.x < D) {
    int d = threadIdx.x;
    float sh = rs_h[d] + rs_h[D + d] + rs_h[2 * D + d] + rs_h[3 * D + d];
    float sh2 = rs_h2[d] + rs_h2[D + d] + rs_h2[2 * D + d] + rs_h2[3 * D + d];
    atomicAdd(&sums[d], sh);
    atomicAdd(&sums[D + d], sh2);
  }
}

__global__ void gn_stats(const float* __restrict__ sums, const float* __restrict__ gn_w,
                         const float* __restrict__ gn_b, const float* __restrict__ gn_ms,
                         float* __restrict__ scsh, float inv_n) {
  int d = threadIdx.x;
  float mean = sums[d] * inv_n;
  float ex2 = sums[D + d] * inv_n;
  float ms = gn_ms[d];
  float var = ex2 - 2.f * ms * mean * mean + ms * ms * mean * mean;
  float inv = 1.f / sqrtf(var + 1e-5f);
  float scale = gn_w[d] * inv;
  float shift = gn_b[d] - ms * mean * scale;
  scsh[d] = scale;
  scsh[D + d] = shift;
}

// ---------------- kernel 5: fused FFN, 32-row tiles (4 blocks/CU) ----------------
__global__ __launch_bounds__(256) void ffn_fused(
    const float* __restrict__ h, const float* __restrict__ scsh,
    const ushort* __restrict__ W1t, const float* __restrict__ b1,
    const ushort* __restrict__ W2t, const float* __restrict__ b2,
    float* __restrict__ out, int n) {
  __shared__ ushort tt[32 * TPAD];  // 33,280 B
  int wv = threadIdx.x >> 6;
  int l = threadIdx.x & 63;
  int lr = l & 15, lg = l >> 4;
  int r0 = blockIdx.x * 32;
  int c0 = wv * 128;
  // ---- GEMM1: t = gelu(hn @ W1 + b1); this wave: cols [c0, c0+128) ----
  {
    f32x4 acc[2][8];
#pragma unroll
    for (int m = 0; m < 2; ++m)
#pragma unroll
      for (int nn = 0; nn < 8; ++nn) acc[m][nn] = (f32x4)0.f;
#pragma unroll
    for (int kb = 0; kb < 4; ++kb) {
      int k0 = kb * 32 + lg * 8;
      float4 s0 = *reinterpret_cast<const float4*>(scsh + k0);
      float4 s1 = *reinterpret_cast<const float4*>(scsh + k0 + 4);
      float4 t0 = *reinterpret_cast<const float4*>(scsh + D + k0);
      float4 t1 = *reinterpret_cast<const float4*>(scsh + D + k0 + 4);
      bf16x8 a[2];
#pragma unroll
      for (int m = 0; m < 2; ++m) {
        int row = r0 + m * 16 + lr;
        row = min(row, n - 1);
        const float* p = h + (size_t)row * D + k0;
        float4 x0 = *reinterpret_cast<const float4*>(p);
        float4 x1 = *reinterpret_cast<const float4*>(p + 4);
        bf16x8 r;
        r[0] = (short)f2bf(x0.x * s0.x + t0.x);
        r[1] = (short)f2bf(x0.y * s0.y + t0.y);
        r[2] = (short)f2bf(x0.z * s0.z + t0.z);
        r[3] = (short)f2bf(x0.w * s0.w + t0.w);
        r[4] = (short)f2bf(x1.x * s1.x + t1.x);
        r[5] = (short)f2bf(x1.y * s1.y + t1.y);
        r[6] = (short)f2bf(x1.z * s1.z + t1.z);
        r[7] = (short)f2bf(x1.w * s1.w + t1.w);
        a[m] = r;
      }
      bf16x8 b[8];
#pragma unroll
      for (int nn = 0; nn < 8; ++nn)
        b[nn] = *reinterpret_cast<const bf16x8*>(W1t + (c0 + nn * 16 + lr) * D + k0);
#pragma unroll
      for (int m = 0; m < 2; ++m)
#pragma unroll
        for (int nn = 0; nn < 8; ++nn)
          acc[m][nn] = __builtin_amdgcn_mfma_f32_16x16x32_bf16(a[m], b[nn], acc[m][nn], 0, 0, 0);
    }
    const float inv_sqrt2 = 0.70710678118654752440f;
#pragma unroll
    for (int m = 0; m < 2; ++m)
#pragma unroll
      for (int nn = 0; nn < 8; ++nn) {
        int col = c0 + nn * 16 + lr;
        float bb = b1[col];
#pragma unroll
        for (int j = 0; j < 4; ++j) {
          int rowl = m * 16 + lg * 4 + j;
          float val = acc[m][nn][j] + bb;
          val = 0.5f * val * (1.f + erff(val * inv_sqrt2));
          tt[rowl * TPAD + col] = f2bf(val);
        }
      }
  }
  __syncthreads();
  // ---- GEMM2: out = hn + t @ W2 + b2; this wave: cols [wv*32, wv*32+32) ----
  {
    f32x4 acc[2][2];
#pragma unroll
    for (int m = 0; m < 2; ++m)
#pragma unroll
      for (int nn = 0; nn < 2; ++nn) acc[m][nn] = (f32x4)0.f;
#pragma unroll 4
    for (int kb = 0; kb < 16; ++kb) {
      int k0 = kb * 32 + lg * 8;
      bf16x8 a[2];
#pragma unroll
      for (int m = 0; m < 2; ++m)
        a[m] = *reinterpret_cast<const bf16x8*>(tt + (m * 16 + lr) * TPAD + k0);
      bf16x8 b[2];
#pragma unroll
      for (int nn = 0; nn < 2; ++nn)
        b[nn] = *reinterpret_cast<const bf16x8*>(W2t + (wv * 32 + nn * 16 + lr) * FF + k0);
#pragma unroll
      for (int m = 0; m < 2; ++m)
#pragma unroll
        for (int nn = 0; nn < 2; ++nn)
          acc[m][nn] = __builtin_amdgcn_mfma_f32_16x16x32_bf16(a[m], b[nn], acc[m][nn], 0, 0, 0);
    }
#pragma unroll
    for (int m = 0; m < 2; ++m)
#pragma unroll
      for (int nn = 0; nn < 2; ++nn) {
        int col = wv * 32 + nn * 16 + lr;
        float bb = b2[col];
        float sc = scsh[col], sh = scsh[D + col];
#pragma unroll
        for (int j = 0; j < 4; ++j) {
          int row = r0 + m * 16 + lg * 4 + j;
          if (row < n) {
            size_t idx = (size_t)row * D + col;
            float hn = h[idx] * sc + sh;
            out[idx] = hn + acc[m][nn][j] + bb;
          }
        }
      }
  }
}

extern "C" void kernel_launch(void* const* d_in, const int* in_sizes, int n_in,
                              void* d_out, int out_size, void* d_ws, size_t ws_size,
                              hipStream_t stream) {
  const float* x     = (const float*)d_in[0];
  const int*   ei    = (const int*)d_in[1];
  const float* attr  = (const float*)d_in[2];
  const float* Wq    = (const float*)d_in[3];
  const float* bq    = (const float*)d_in[4];
  const float* Wk    = (const float*)d_in[5];
  const float* bk    = (const float*)d_in[6];
  const float* Wv    = (const float*)d_in[7];
  const float* bv    = (const float*)d_in[8];
  const float* We    = (const float*)d_in[9];
  const float* Wskip = (const float*)d_in[10];
  const float* bskip = (const float*)d_in[11];
  const float* Wbeta = (const float*)d_in[12];
  const float* gn_w  = (const float*)d_in[13];
  const float* gn_b  = (const float*)d_in[14];
  const float* gn_ms = (const float*)d_in[15];
  const float* W1    = (const float*)d_in[16];
  const float* b1    = (const float*)d_in[17];
  const float* W2    = (const float*)d_in[18];
  const float* b2    = (const float*)d_in[19];

  const int n = in_sizes[0] / D;
  const int E = in_sizes[1] / 2;
  const int* src = ei;
  const int* dst = ei + E;
  const size_t ND = (size_t)n * D;

  // ---- workspace layout ----
  ushort* qb = (ushort*)d_ws;                 // ND bf16
  ushort* kvb = qb + ND;                      // 2*ND bf16 (k,v interleaved per feature-pair)
  float* xr = (float*)(kvb + 2 * ND);         // ND f32
  int* deg = (int*)(xr + ND);                 // n    (zeroed)
  int* cursor = deg + n;                      // n    (zeroed)
  float* sums = (float*)(cursor + n);         // 2D   (zeroed)
  int* off = (int*)(sums + 2 * D);            // n+1
  int* sorted = off + n + 1;                  // E
  ushort* Wcat_t = (ushort*)(sorted + E);     // 4*D*D
  ushort* W1t = Wcat_t + 4 * D * D;           // D*FF
  ushort* W2t = W1t + D * FF;                 // FF*D
  float* bcat = (float*)(W2t + FF * D);       // 4D
  float* scsh = bcat + 4 * D;                 // 2D

  (void)hipMemsetAsync(deg, 0, (2 * (size_t)n + 2 * D) * sizeof(int), stream);

  int ghist = (E + 255) / 256;
  prep_hist<<<256 + ghist, 256, 0, stream>>>(Wq, Wk, Wv, Wskip, bq, bk, bv, bskip, W1, W2,
                                             dst, deg, E, Wcat_t, bcat, W1t, W2t);
  scan_kernel<<<1, 1024, 0, stream>>>(deg, off, n);

  int gm = (n + 63) / 64;
  gemm_scatter<<<gm + ghist, 256, 0, stream>>>(x, Wcat_t, bcat, qb, kvb, xr, n, gm, dst,
                                               off, cursor, sorted, E);

  node_attn<<<2048, 256, 0, stream>>>(src, sorted, off, attr, We, qb, kvb, xr, x, Wbeta,
                                      (float*)d_out, sums, n);
  gn_stats<<<1, 128, 0, stream>>>(sums, gn_w, gn_b, gn_ms, scsh, 1.f / (float)n);

  ffn_fused<<<(n + 31) / 32, 256, 0, stream>>>((const float*)d_out, scsh, W1t, b1, W2t, b2,
                                               (float*)d_out, n);
}

// Round 7
// 473.923 us; speedup vs baseline: 5.3137x; 1.1003x over previous
//
#include <hip/hip_runtime.h>
#include <hip/hip_fp16.h>
#include <math.h>

#define D 128
#define ED 10
#define FF 512
#define TPAD 520   // bf16 elements per LDS row in ffn (512 + 8 pad)
#define XPAD 136   // bf16 elements per LDS row in gemm_in (128 + 8 pad; 272B = 17*16B)

typedef __attribute__((ext_vector_type(4))) float f32x4;
typedef __attribute__((ext_vector_type(8))) short bf16x8;
using h2 = decltype(__builtin_amdgcn_cvt_pkrtz(0.f, 0.f));  // __fp16 ext_vector(2)

__device__ __forceinline__ ushort f2bf(float f) {
  unsigned u = __float_as_uint(f);
  unsigned r = u + 0x7fffu + ((u >> 16) & 1u);
  return (ushort)(r >> 16);
}
__device__ __forceinline__ float bf2f(ushort u) {
  return __uint_as_float(((unsigned)u) << 16);
}

// ---------------- kernel 1: weight prep (blocks 0..255) + degree hist + edge rank ------
__global__ void prep_hist(const float* __restrict__ Wq, const float* __restrict__ Wk,
                          const float* __restrict__ Wv, const float* __restrict__ Wskip,
                          const float* __restrict__ bq, const float* __restrict__ bk,
                          const float* __restrict__ bv, const float* __restrict__ bskip,
                          const float* __restrict__ W1, const float* __restrict__ W2,
                          const int* __restrict__ dst, int* __restrict__ deg,
                          int* __restrict__ rank, int E,
                          ushort* __restrict__ Wcat_t, float* __restrict__ bcat,
                          ushort* __restrict__ W1t, ushort* __restrict__ W2t) {
  int b = blockIdx.x;
  if (b >= 256) {
    int t = (b - 256) * 256 + threadIdx.x;
    if (t < E) rank[t] = atomicAdd(&deg[dst[t]], 1);
    return;
  }
  int t = b * 256 + threadIdx.x;  // 0..65535
  {
    int w = t >> 14, c = (t >> 7) & 127, kk = t & 127;
    const float* W = (w == 0) ? Wq : (w == 1) ? Wk : (w == 2) ? Wv : Wskip;
    Wcat_t[t] = f2bf(W[kk * D + c]);
  }
  {
    int f = t >> 7, kk = t & 127;
    W1t[t] = f2bf(W1[kk * FF + f]);
  }
  {
    int c = t >> 9, f = t & 511;
    W2t[t] = f2bf(W2[f * D + c]);
  }
  if (t < 4 * D) {
    int w = t >> 7;
    const float* bb = (w == 0) ? bq : (w == 1) ? bk : (w == 2) ? bv : bskip;
    bcat[t] = bb[t & 127];
  }
}

// ---------------- kernel 2: exclusive scan of deg -> off[0..n] ----------------
__global__ __launch_bounds__(1024) void scan_kernel(const int* __restrict__ deg,
                                                    int* __restrict__ off, int n) {
  __shared__ int part[1024];
  int t = threadIdx.x;
  int chunk = (n + 1023) / 1024;
  int lo = t * chunk, hi = min(lo + chunk, n);
  int s = 0;
  for (int i = lo; i < hi; ++i) s += deg[i];
  part[t] = s;
  __syncthreads();
  for (int dd = 1; dd < 1024; dd <<= 1) {
    int v = (t >= dd) ? part[t - dd] : 0;
    __syncthreads();
    part[t] += v;
    __syncthreads();
  }
  int excl = (t == 0) ? 0 : part[t - 1];
  for (int i = lo; i < hi; ++i) {
    off[i] = excl;
    excl += deg[i];
  }
  if (t == 1023) off[n] = part[1023];
}

// ---------------- kernel 3: CSR scatter (no atomics: rank precomputed) ----------------
__global__ void scatter_kernel(const int* __restrict__ dst, const int* __restrict__ rank,
                               const int* __restrict__ off, int* __restrict__ sorted, int E) {
  int t = blockIdx.x * blockDim.x + threadIdx.x;
  if (t >= E) return;
  sorted[off[dst[t]] + rank[t]] = t;
}

// ---------------- kernel 4: fused q/kv/xr GEMM, LDS-staged A ----------------
// block = 32 rows, 4 waves; wave 0->q (bf16), 1->k, 2->v (interleaved kvb), 3->xr (f32)
__global__ __launch_bounds__(256) void gemm_in(
    const float* __restrict__ x, const ushort* __restrict__ Wcat_t,
    const float* __restrict__ bcat, ushort* __restrict__ qb, ushort* __restrict__ kvb,
    float* __restrict__ xr, int n) {
  __shared__ ushort xa[32 * XPAD];  // 8704 B
  int r0 = blockIdx.x * 32;
  // ---- stage x tile [32][128] -> LDS bf16, coalesced ----
  {
    int row = threadIdx.x >> 3;   // 0..31
    int seg = threadIdx.x & 7;    // 16 floats each
    int grow = min(r0 + row, n - 1);
    const float4* p = reinterpret_cast<const float4*>(x + (size_t)grow * D + seg * 16);
    float4 f0 = p[0], f1 = p[1], f2 = p[2], f3 = p[3];
    bf16x8 u0, u1;
    u0[0] = (short)f2bf(f0.x); u0[1] = (short)f2bf(f0.y);
    u0[2] = (short)f2bf(f0.z); u0[3] = (short)f2bf(f0.w);
    u0[4] = (short)f2bf(f1.x); u0[5] = (short)f2bf(f1.y);
    u0[6] = (short)f2bf(f1.z); u0[7] = (short)f2bf(f1.w);
    u1[0] = (short)f2bf(f2.x); u1[1] = (short)f2bf(f2.y);
    u1[2] = (short)f2bf(f2.z); u1[3] = (short)f2bf(f2.w);
    u1[4] = (short)f2bf(f3.x); u1[5] = (short)f2bf(f3.y);
    u1[6] = (short)f2bf(f3.z); u1[7] = (short)f2bf(f3.w);
    ushort* dl = xa + row * XPAD + seg * 16;
    *reinterpret_cast<bf16x8*>(dl) = u0;
    *reinterpret_cast<bf16x8*>(dl + 8) = u1;
  }
  __syncthreads();
  int wv = threadIdx.x >> 6;
  int l = threadIdx.x & 63;
  int lr = l & 15, lg = l >> 4;
  const ushort* Wt = Wcat_t + wv * D * D;
  f32x4 acc[2][8];
#pragma unroll
  for (int m = 0; m < 2; ++m)
#pragma unroll
    for (int nn = 0; nn < 8; ++nn) acc[m][nn] = (f32x4)0.f;
#pragma unroll
  for (int kb2 = 0; kb2 < 4; ++kb2) {
    int k0 = kb2 * 32 + lg * 8;
    bf16x8 a[2];
#pragma unroll
    for (int m = 0; m < 2; ++m)
      a[m] = *reinterpret_cast<const bf16x8*>(xa + (m * 16 + lr) * XPAD + k0);
    bf16x8 b[8];
#pragma unroll
    for (int nn = 0; nn < 8; ++nn)
      b[nn] = *reinterpret_cast<const bf16x8*>(Wt + (nn * 16 + lr) * D + k0);
#pragma unroll
    for (int m = 0; m < 2; ++m)
#pragma unroll
      for (int nn = 0; nn < 8; ++nn)
        acc[m][nn] = __builtin_amdgcn_mfma_f32_16x16x32_bf16(a[m], b[nn], acc[m][nn], 0, 0, 0);
  }
#pragma unroll
  for (int m = 0; m < 2; ++m)
#pragma unroll
    for (int nn = 0; nn < 8; ++nn) {
      int col = nn * 16 + lr;
      float bb = bcat[wv * D + col];
#pragma unroll
      for (int j = 0; j < 4; ++j) {
        int row = r0 + m * 16 + lg * 4 + j;
        if (row < n) {
          float val = acc[m][nn][j] + bb;
          if (wv == 0) qb[(size_t)row * D + col] = f2bf(val);
          else if (wv == 1) kvb[((size_t)row * 64 + (col >> 1)) * 4 + (col & 1)] = f2bf(val);
          else if (wv == 2) kvb[((size_t)row * 64 + (col >> 1)) * 4 + 2 + (col & 1)] = f2bf(val);
          else xr[(size_t)row * D + col] = val;
        }
      }
    }
}

// ---------------- kernel 5: node-centric attention + beta gate + residual + GN sums ----
__global__ __launch_bounds__(256) void node_attn(
    const int* __restrict__ src, const int* __restrict__ sorted,
    const int* __restrict__ off, const float* __restrict__ attr,
    const float* __restrict__ We, const ushort* __restrict__ qb,
    const ushort* __restrict__ kvb, const float* __restrict__ xr,
    const float* __restrict__ x, const float* __restrict__ Wbeta,
    float* __restrict__ h, float* __restrict__ sums, int n) {
  __shared__ h2 attrS[4][64][5];  // per-wave staged edge attrs (half2), 5.1 KB
  __shared__ float rs_h[4 * D], rs_h2[4 * D];
  int wid = threadIdx.x >> 6;
  int l = threadIdx.x & 63;
  int d0 = 2 * l;
  h2 wA[5], wB[5];
#pragma unroll
  for (int t = 0; t < 5; ++t) {
    wA[t] = __builtin_amdgcn_cvt_pkrtz(We[(2 * t) * D + d0], We[(2 * t + 1) * D + d0]);
    wB[t] = __builtin_amdgcn_cvt_pkrtz(We[(2 * t) * D + d0 + 1], We[(2 * t + 1) * D + d0 + 1]);
  }
  float2 wb0 = *reinterpret_cast<const float2*>(Wbeta + d0);
  float2 wb1 = *reinterpret_cast<const float2*>(Wbeta + D + d0);
  float2 wb2 = *reinterpret_cast<const float2*>(Wbeta + 2 * D + d0);
  float s_h0 = 0.f, s_h20 = 0.f, s_h1 = 0.f, s_h21 = 0.f;
  for (int node = blockIdx.x * 4 + wid; node < n; node += gridDim.x * 4) {
    const ushort2 qu = *reinterpret_cast<const ushort2*>(qb + (size_t)node * D + d0);
    float q0 = bf2f(qu.x) * 0.25f, q1 = bf2f(qu.y) * 0.25f;  // fold 1/sqrt(C)
    int o0 = off[node], dg = off[node + 1] - o0;
    float m = -1e30f, den = 0.f, acc0 = 0.f, acc1 = 0.f;
    for (int chunk = 0; chunk < dg; chunk += 64) {
      int cnt = min(64, dg - chunk);
      int s_l = 0;
      {
        int e_l = 0;
        if (chunk + l < dg) {
          e_l = sorted[o0 + chunk + l];
          s_l = src[e_l];
        }
        const float2* ap = reinterpret_cast<const float2*>(attr + (size_t)e_l * ED);
#pragma unroll
        for (int j = 0; j < 5; ++j) {
          float2 av = ap[j];
          attrS[wid][l][j] = __builtin_amdgcn_cvt_pkrtz(av.x, av.y);
        }
      }
      int s_nx = __shfl(s_l, 0);
      ushort4 kv_n = *reinterpret_cast<const ushort4*>(kvb + ((size_t)s_nx * 64 + l) * 4);
      for (int i = 0; i < cnt; ++i) {
        ushort4 kv = kv_n;
        if (i + 1 < cnt) {
          int s2 = __shfl(s_l, i + 1);
          kv_n = *reinterpret_cast<const ushort4*>(kvb + ((size_t)s2 * 64 + l) * 4);
        }
        h2 a0 = attrS[wid][i][0], a1 = attrS[wid][i][1], a2 = attrS[wid][i][2],
           a3 = attrS[wid][i][3], a4 = attrS[wid][i][4];
        float ec0 = __builtin_amdgcn_fdot2(a0, wA[0], 0.f, false);
        ec0 = __builtin_amdgcn_fdot2(a1, wA[1], ec0, false);
        ec0 = __builtin_amdgcn_fdot2(a2, wA[2], ec0, false);
        ec0 = __builtin_amdgcn_fdot2(a3, wA[3], ec0, false);
        ec0 = __builtin_amdgcn_fdot2(a4, wA[4], ec0, false);
        float ec1 = __builtin_amdgcn_fdot2(a0, wB[0], 0.f, false);
        ec1 = __builtin_amdgcn_fdot2(a1, wB[1], ec1, false);
        ec1 = __builtin_amdgcn_fdot2(a2, wB[2], ec1, false);
        ec1 = __builtin_amdgcn_fdot2(a3, wB[3], ec1, false);
        ec1 = __builtin_amdgcn_fdot2(a4, wB[4], ec1, false);
        float kk0 = bf2f(kv.x) + ec0, kk1 = bf2f(kv.y) + ec1;
        float vv0 = bf2f(kv.z) + ec0, vv1 = bf2f(kv.w) + ec1;
        float p = fmaf(q0, kk0, q1 * kk1);
        p += __shfl_xor(p, 1, 8);
        p += __shfl_xor(p, 2, 8);
        p += __shfl_xor(p, 4, 8);
        if (__any(p > m + 8.f)) {
          float mn = fmaxf(m, p);
          float sc = __expf(m - mn);
          den *= sc; acc0 *= sc; acc1 *= sc;
          m = mn;
        }
        float ex = __expf(p - m);
        den += ex;
        acc0 = fmaf(ex, vv0, acc0);
        acc1 = fmaf(ex, vv1, acc1);
      }
    }
    float inv = 1.f / (den + 1e-16f);
    float oo0 = acc0 * inv, oo1 = acc1 * inv;
    float2 xr2 = *reinterpret_cast<const float2*>(xr + (size_t)node * D + d0);
    float2 x2 = *reinterpret_cast<const float2*>(x + (size_t)node * D + d0);
    float pb = oo0 * wb0.x + xr2.x * wb1.x + (oo0 - xr2.x) * wb2.x
             + oo1 * wb0.y + xr2.y * wb1.y + (oo1 - xr2.y) * wb2.y;
#pragma unroll
    for (int msk = 1; msk < 64; msk <<= 1) pb += __shfl_xor(pb, msk, 64);
    float beta = 1.f / (1.f + __expf(-pb));
    float h0 = x2.x + beta * xr2.x + (1.f - beta) * oo0;
    float h1 = x2.y + beta * xr2.y + (1.f - beta) * oo1;
    *reinterpret_cast<float2*>(h + (size_t)node * D + d0) = make_float2(h0, h1);
    s_h0 += h0; s_h20 += h0 * h0;
    s_h1 += h1; s_h21 += h1 * h1;
  }
  rs_h[wid * D + d0] = s_h0;   rs_h[wid * D + d0 + 1] = s_h1;
  rs_h2[wid * D + d0] = s_h20; rs_h2[wid * D + d0 + 1] = s_h21;
  __syncthreads();
  if (threadIdx.x < D) {
    int d = threadIdx.x;
    float sh = rs_h[d] + rs_h[D + d] + rs_h[2 * D + d] + rs_h[3 * D + d];
    float sh2 = rs_h2[d] + rs_h2[D + d] + rs_h2[2 * D + d] + rs_h2[3 * D + d];
    atomicAdd(&sums[d], sh);
    atomicAdd(&sums[D + d], sh2);
  }
}

__global__ void gn_stats(const float* __restrict__ sums, const float* __restrict__ gn_w,
                         const float* __restrict__ gn_b, const float* __restrict__ gn_ms,
                         float* __restrict__ scsh, float inv_n) {
  int d = threadIdx.x;
  float mean = sums[d] * inv_n;
  float ex2 = sums[D + d] * inv_n;
  float ms = gn_ms[d];
  float var = ex2 - 2.f * ms * mean * mean + ms * ms * mean * mean;
  float inv = 1.f / sqrtf(var + 1e-5f);
  float scale = gn_w[d] * inv;
  float shift = gn_b[d] - ms * mean * scale;
  scsh[d] = scale;
  scsh[D + d] = shift;
}

// ---------------- kernel 6: fused FFN, 32-row tiles ----------------
__global__ __launch_bounds__(256) void ffn_fused(
    const float* __restrict__ h, const float* __restrict__ scsh,
    const ushort* __restrict__ W1t, const float* __restrict__ b1,
    const ushort* __restrict__ W2t, const float* __restrict__ b2,
    float* __restrict__ out, int n) {
  __shared__ ushort tt[32 * TPAD];  // 33,280 B
  int wv = threadIdx.x >> 6;
  int l = threadIdx.x & 63;
  int lr = l & 15, lg = l >> 4;
  int r0 = blockIdx.x * 32;
  int c0 = wv * 128;
  {
    f32x4 acc[2][8];
#pragma unroll
    for (int m = 0; m < 2; ++m)
#pragma unroll
      for (int nn = 0; nn < 8; ++nn) acc[m][nn] = (f32x4)0.f;
#pragma unroll
    for (int kb = 0; kb < 4; ++kb) {
      int k0 = kb * 32 + lg * 8;
      float4 s0 = *reinterpret_cast<const float4*>(scsh + k0);
      float4 s1 = *reinterpret_cast<const float4*>(scsh + k0 + 4);
      float4 t0 = *reinterpret_cast<const float4*>(scsh + D + k0);
      float4 t1 = *reinterpret_cast<const float4*>(scsh + D + k0 + 4);
      bf16x8 a[2];
#pragma unroll
      for (int m = 0; m < 2; ++m) {
        int row = r0 + m * 16 + lr;
        row = min(row, n - 1);
        const float* p = h + (size_t)row * D + k0;
        float4 x0 = *reinterpret_cast<const float4*>(p);
        float4 x1 = *reinterpret_cast<const float4*>(p + 4);
        bf16x8 r;
        r[0] = (short)f2bf(x0.x * s0.x + t0.x);
        r[1] = (short)f2bf(x0.y * s0.y + t0.y);
        r[2] = (short)f2bf(x0.z * s0.z + t0.z);
        r[3] = (short)f2bf(x0.w * s0.w + t0.w);
        r[4] = (short)f2bf(x1.x * s1.x + t1.x);
        r[5] = (short)f2bf(x1.y * s1.y + t1.y);
        r[6] = (short)f2bf(x1.z * s1.z + t1.z);
        r[7] = (short)f2bf(x1.w * s1.w + t1.w);
        a[m] = r;
      }
      bf16x8 b[8];
#pragma unroll
      for (int nn = 0; nn < 8; ++nn)
        b[nn] = *reinterpret_cast<const bf16x8*>(W1t + (c0 + nn * 16 + lr) * D + k0);
#pragma unroll
      for (int m = 0; m < 2; ++m)
#pragma unroll
        for (int nn = 0; nn < 8; ++nn)
          acc[m][nn] = __builtin_amdgcn_mfma_f32_16x16x32_bf16(a[m], b[nn], acc[m][nn], 0, 0, 0);
    }
    const float inv_sqrt2 = 0.70710678118654752440f;
#pragma unroll
    for (int m = 0; m < 2; ++m)
#pragma unroll
      for (int nn = 0; nn < 8; ++nn) {
        int col = c0 + nn * 16 + lr;
        float bb = b1[col];
#pragma unroll
        for (int j = 0; j < 4; ++j) {
          int rowl = m * 16 + lg * 4 + j;
          float val = acc[m][nn][j] + bb;
          val = 0.5f * val * (1.f + erff(val * inv_sqrt2));
          tt[rowl * TPAD + col] = f2bf(val);
        }
      }
  }
  __syncthreads();
  {
    f32x4 acc[2][2];
#pragma unroll
    for (int m = 0; m < 2; ++m)
#pragma unroll
      for (int nn = 0; nn < 2; ++nn) acc[m][nn] = (f32x4)0.f;
#pragma unroll 4
    for (int kb = 0; kb < 16; ++kb) {
      int k0 = kb * 32 + lg * 8;
      bf16x8 a[2];
#pragma unroll
      for (int m = 0; m < 2; ++m)
        a[m] = *reinterpret_cast<const bf16x8*>(tt + (m * 16 + lr) * TPAD + k0);
      bf16x8 b[2];
#pragma unroll
      for (int nn = 0; nn < 2; ++nn)
        b[nn] = *reinterpret_cast<const bf16x8*>(W2t + (wv * 32 + nn * 16 + lr) * FF + k0);
#pragma unroll
      for (int m = 0; m < 2; ++m)
#pragma unroll
        for (int nn = 0; nn < 2; ++nn)
          acc[m][nn] = __builtin_amdgcn_mfma_f32_16x16x32_bf16(a[m], b[nn], acc[m][nn], 0, 0, 0);
    }
#pragma unroll
    for (int m = 0; m < 2; ++m)
#pragma unroll
      for (int nn = 0; nn < 2; ++nn) {
        int col = wv * 32 + nn * 16 + lr;
        float bb = b2[col];
        float sc = scsh[col], sh = scsh[D + col];
#pragma unroll
        for (int j = 0; j < 4; ++j) {
          int row = r0 + m * 16 + lg * 4 + j;
          if (row < n) {
            size_t idx = (size_t)row * D + col;
            float hn = h[idx] * sc + sh;
            out[idx] = hn + acc[m][nn][j] + bb;
          }
        }
      }
  }
}

extern "C" void kernel_launch(void* const* d_in, const int* in_sizes, int n_in,
                              void* d_out, int out_size, void* d_ws, size_t ws_size,
                              hipStream_t stream) {
  const float* x     = (const float*)d_in[0];
  const int*   ei    = (const int*)d_in[1];
  const float* attr  = (const float*)d_in[2];
  const float* Wq    = (const float*)d_in[3];
  const float* bq    = (const float*)d_in[4];
  const float* Wk    = (const float*)d_in[5];
  const float* bk    = (const float*)d_in[6];
  const float* Wv    = (const float*)d_in[7];
  const float* bv    = (const float*)d_in[8];
  const float* We    = (const float*)d_in[9];
  const float* Wskip = (const float*)d_in[10];
  const float* bskip = (const float*)d_in[11];
  const float* Wbeta = (const float*)d_in[12];
  const float* gn_w  = (const float*)d_in[13];
  const float* gn_b  = (const float*)d_in[14];
  const float* gn_ms = (const float*)d_in[15];
  const float* W1    = (const float*)d_in[16];
  const float* b1    = (const float*)d_in[17];
  const float* W2    = (const float*)d_in[18];
  const float* b2    = (const float*)d_in[19];

  const int n = in_sizes[0] / D;
  const int E = in_sizes[1] / 2;
  const int* src = ei;
  const int* dst = ei + E;
  const size_t ND = (size_t)n * D;

  // ---- workspace layout ----
  ushort* qb = (ushort*)d_ws;                 // ND bf16
  ushort* kvb = qb + ND;                      // 2*ND bf16 (k,v interleaved per feature-pair)
  float* xr = (float*)(kvb + 2 * ND);         // ND f32
  int* deg = (int*)(xr + ND);                 // n    (zeroed)
  float* sums = (float*)(deg + n);            // 2D   (zeroed)
  int* off = (int*)(sums + 2 * D);            // n+1
  int* sorted = off + n + 1;                  // E
  int* rank = sorted + E;                     // E
  ushort* Wcat_t = (ushort*)(rank + E);       // 4*D*D
  ushort* W1t = Wcat_t + 4 * D * D;           // D*FF
  ushort* W2t = W1t + D * FF;                 // FF*D
  float* bcat = (float*)(W2t + FF * D);       // 4D
  float* scsh = bcat + 4 * D;                 // 2D

  (void)hipMemsetAsync(deg, 0, ((size_t)n + 2 * D) * sizeof(int), stream);

  int ghist = (E + 255) / 256;
  prep_hist<<<256 + ghist, 256, 0, stream>>>(Wq, Wk, Wv, Wskip, bq, bk, bv, bskip, W1, W2,
                                             dst, deg, rank, E, Wcat_t, bcat, W1t, W2t);
  scan_kernel<<<1, 1024, 0, stream>>>(deg, off, n);
  scatter_kernel<<<ghist, 256, 0, stream>>>(dst, rank, off, sorted, E);

  gemm_in<<<(n + 31) / 32, 256, 0, stream>>>(x, Wcat_t, bcat, qb, kvb, xr, n);

  node_attn<<<2048, 256, 0, stream>>>(src, sorted, off, attr, We, qb, kvb, xr, x, Wbeta,
                                      (float*)d_out, sums, n);
  gn_stats<<<1, 128, 0, stream>>>(sums, gn_w, gn_b, gn_ms, scsh, 1.f / (float)n);

  ffn_fused<<<(n + 31) / 32, 256, 0, stream>>>((const float*)d_out, scsh, W1t, b1, W2t, b2,
                                               (float*)d_out, n);
}

// Round 8
// 433.866 us; speedup vs baseline: 5.8043x; 1.0923x over previous
//
#include <hip/hip_runtime.h>
#include <hip/hip_fp16.h>
#include <math.h>

#define D 128
#define ED 10
#define FF 512
#define TPAD 520   // bf16 per LDS row in ffn t-tile (512 + 8 pad)
#define XPAD 136   // bf16 per LDS row for 128-wide tiles (128 + 8 pad)

typedef __attribute__((ext_vector_type(4))) float f32x4;
typedef __attribute__((ext_vector_type(8))) short bf16x8;
using h2 = decltype(__builtin_amdgcn_cvt_pkrtz(0.f, 0.f));  // __fp16 ext_vector(2)

__device__ __forceinline__ ushort f2bf(float f) {
  unsigned u = __float_as_uint(f);
  unsigned r = u + 0x7fffu + ((u >> 16) & 1u);
  return (ushort)(r >> 16);
}
__device__ __forceinline__ float bf2f(ushort u) {
  return __uint_as_float(((unsigned)u) << 16);
}

// ---------------- kernel 1: weight prep (blocks 0..255) + degree hist + edge rank ------
__global__ void prep_hist(const float* __restrict__ Wq, const float* __restrict__ Wk,
                          const float* __restrict__ Wv, const float* __restrict__ Wskip,
                          const float* __restrict__ bq, const float* __restrict__ bk,
                          const float* __restrict__ bv, const float* __restrict__ bskip,
                          const float* __restrict__ W1, const float* __restrict__ W2,
                          const int* __restrict__ dst, int* __restrict__ deg,
                          int* __restrict__ rank, int E,
                          ushort* __restrict__ Wcat_t, float* __restrict__ bcat,
                          ushort* __restrict__ W1t, ushort* __restrict__ W2t) {
  int b = blockIdx.x;
  if (b >= 256) {
    int t = (b - 256) * 256 + threadIdx.x;
    if (t < E) rank[t] = atomicAdd(&deg[dst[t]], 1);
    return;
  }
  int t = b * 256 + threadIdx.x;  // 0..65535
  {
    int w = t >> 14, c = (t >> 7) & 127, kk = t & 127;
    const float* W = (w == 0) ? Wq : (w == 1) ? Wk : (w == 2) ? Wv : Wskip;
    Wcat_t[t] = f2bf(W[kk * D + c]);
  }
  {
    int f = t >> 7, kk = t & 127;
    W1t[t] = f2bf(W1[kk * FF + f]);
  }
  {
    int c = t >> 9, f = t & 511;
    W2t[t] = f2bf(W2[f * D + c]);
  }
  if (t < 4 * D) {
    int w = t >> 7;
    const float* bb = (w == 0) ? bq : (w == 1) ? bk : (w == 2) ? bv : bskip;
    bcat[t] = bb[t & 127];
  }
}

// ---------------- kernel 2: exclusive scan of deg -> off[0..n] ----------------
__global__ __launch_bounds__(1024) void scan_kernel(const int* __restrict__ deg,
                                                    int* __restrict__ off, int n) {
  __shared__ int part[1024];
  int t = threadIdx.x;
  int chunk = (n + 1023) / 1024;
  int lo = t * chunk, hi = min(lo + chunk, n);
  int s = 0;
  for (int i = lo; i < hi; ++i) s += deg[i];
  part[t] = s;
  __syncthreads();
  for (int dd = 1; dd < 1024; dd <<= 1) {
    int v = (t >= dd) ? part[t - dd] : 0;
    __syncthreads();
    part[t] += v;
    __syncthreads();
  }
  int excl = (t == 0) ? 0 : part[t - 1];
  for (int i = lo; i < hi; ++i) {
    off[i] = excl;
    excl += deg[i];
  }
  if (t == 1023) off[n] = part[1023];
}

// ---------------- kernel 3: CSR scatter (no atomics: rank precomputed) ----------------
__global__ void scatter_kernel(const int* __restrict__ dst, const int* __restrict__ rank,
                               const int* __restrict__ off, int* __restrict__ sorted, int E) {
  int t = blockIdx.x * blockDim.x + threadIdx.x;
  if (t >= E) return;
  sorted[off[dst[t]] + rank[t]] = t;
}

// ---------------- kernel 4: fused q/kv/xr GEMM, LDS-staged A ----------------
__global__ __launch_bounds__(256) void gemm_in(
    const float* __restrict__ x, const ushort* __restrict__ Wcat_t,
    const float* __restrict__ bcat, ushort* __restrict__ qb, ushort* __restrict__ kvb,
    float* __restrict__ xr, int n) {
  __shared__ ushort xa[32 * XPAD];  // 8704 B
  int r0 = blockIdx.x * 32;
  {
    int row = threadIdx.x >> 3;   // 0..31
    int seg = threadIdx.x & 7;    // 16 floats each
    int grow = min(r0 + row, n - 1);
    const float4* p = reinterpret_cast<const float4*>(x + (size_t)grow * D + seg * 16);
    float4 f0 = p[0], f1 = p[1], f2 = p[2], f3 = p[3];
    bf16x8 u0, u1;
    u0[0] = (short)f2bf(f0.x); u0[1] = (short)f2bf(f0.y);
    u0[2] = (short)f2bf(f0.z); u0[3] = (short)f2bf(f0.w);
    u0[4] = (short)f2bf(f1.x); u0[5] = (short)f2bf(f1.y);
    u0[6] = (short)f2bf(f1.z); u0[7] = (short)f2bf(f1.w);
    u1[0] = (short)f2bf(f2.x); u1[1] = (short)f2bf(f2.y);
    u1[2] = (short)f2bf(f2.z); u1[3] = (short)f2bf(f2.w);
    u1[4] = (short)f2bf(f3.x); u1[5] = (short)f2bf(f3.y);
    u1[6] = (short)f2bf(f3.z); u1[7] = (short)f2bf(f3.w);
    ushort* dl = xa + row * XPAD + seg * 16;
    *reinterpret_cast<bf16x8*>(dl) = u0;
    *reinterpret_cast<bf16x8*>(dl + 8) = u1;
  }
  __syncthreads();
  int wv = threadIdx.x >> 6;
  int l = threadIdx.x & 63;
  int lr = l & 15, lg = l >> 4;
  const ushort* Wt = Wcat_t + wv * D * D;
  f32x4 acc[2][8];
#pragma unroll
  for (int m = 0; m < 2; ++m)
#pragma unroll
    for (int nn = 0; nn < 8; ++nn) acc[m][nn] = (f32x4)0.f;
#pragma unroll
  for (int kb2 = 0; kb2 < 4; ++kb2) {
    int k0 = kb2 * 32 + lg * 8;
    bf16x8 a[2];
#pragma unroll
    for (int m = 0; m < 2; ++m)
      a[m] = *reinterpret_cast<const bf16x8*>(xa + (m * 16 + lr) * XPAD + k0);
    bf16x8 b[8];
#pragma unroll
    for (int nn = 0; nn < 8; ++nn)
      b[nn] = *reinterpret_cast<const bf16x8*>(Wt + (nn * 16 + lr) * D + k0);
#pragma unroll
    for (int m = 0; m < 2; ++m)
#pragma unroll
      for (int nn = 0; nn < 8; ++nn)
        acc[m][nn] = __builtin_amdgcn_mfma_f32_16x16x32_bf16(a[m], b[nn], acc[m][nn], 0, 0, 0);
  }
#pragma unroll
  for (int m = 0; m < 2; ++m)
#pragma unroll
    for (int nn = 0; nn < 8; ++nn) {
      int col = nn * 16 + lr;
      float bb = bcat[wv * D + col];
#pragma unroll
      for (int j = 0; j < 4; ++j) {
        int row = r0 + m * 16 + lg * 4 + j;
        if (row < n) {
          float val = acc[m][nn][j] + bb;
          if (wv == 0) qb[(size_t)row * D + col] = f2bf(val);
          else if (wv == 1) kvb[((size_t)row * 64 + (col >> 1)) * 4 + (col & 1)] = f2bf(val);
          else if (wv == 2) kvb[((size_t)row * 64 + (col >> 1)) * 4 + 2 + (col & 1)] = f2bf(val);
          else xr[(size_t)row * D + col] = val;
        }
      }
    }
}

// ---------------- kernel 5: node-centric attention, 4-deep pipelined ----------------
__global__ __launch_bounds__(256) void node_attn(
    const int* __restrict__ src, const int* __restrict__ sorted,
    const int* __restrict__ off, const float* __restrict__ attr,
    const float* __restrict__ We, const ushort* __restrict__ qb,
    const ushort* __restrict__ kvb, const float* __restrict__ xr,
    const float* __restrict__ x, const float* __restrict__ Wbeta,
    float* __restrict__ h, float* __restrict__ sums, int n) {
  __shared__ h2 attrS[4][64][5];
  __shared__ float rs_h[4 * D], rs_h2[4 * D];
  int wid = threadIdx.x >> 6;
  int l = threadIdx.x & 63;
  int d0 = 2 * l;
  h2 wA[5], wB[5];
#pragma unroll
  for (int t = 0; t < 5; ++t) {
    wA[t] = __builtin_amdgcn_cvt_pkrtz(We[(2 * t) * D + d0], We[(2 * t + 1) * D + d0]);
    wB[t] = __builtin_amdgcn_cvt_pkrtz(We[(2 * t) * D + d0 + 1], We[(2 * t + 1) * D + d0 + 1]);
  }
  float2 wb0 = *reinterpret_cast<const float2*>(Wbeta + d0);
  float2 wb1 = *reinterpret_cast<const float2*>(Wbeta + D + d0);
  float2 wb2 = *reinterpret_cast<const float2*>(Wbeta + 2 * D + d0);
  float s_h0 = 0.f, s_h20 = 0.f, s_h1 = 0.f, s_h21 = 0.f;
  for (int node = blockIdx.x * 4 + wid; node < n; node += gridDim.x * 4) {
    const ushort2 qu = *reinterpret_cast<const ushort2*>(qb + (size_t)node * D + d0);
    float q0 = bf2f(qu.x) * 0.25f, q1 = bf2f(qu.y) * 0.25f;
    int o0 = off[node], dg = off[node + 1] - o0;
    float m = -1e30f, den = 0.f, acc0 = 0.f, acc1 = 0.f;
    for (int chunk = 0; chunk < dg; chunk += 64) {
      int cnt = min(64, dg - chunk);
      int s_l = 0;
      {
        int e_l = 0;
        if (chunk + l < dg) {
          e_l = sorted[o0 + chunk + l];
          s_l = src[e_l];
        }
        const float2* ap = reinterpret_cast<const float2*>(attr + (size_t)e_l * ED);
#pragma unroll
        for (int j = 0; j < 5; ++j) {
          float2 av = ap[j];
          attrS[wid][l][j] = __builtin_amdgcn_cvt_pkrtz(av.x, av.y);
        }
      }
      auto LD = [&](int idx) -> ushort4 {
        int ss = __shfl(s_l, min(idx, cnt - 1));
        return *reinterpret_cast<const ushort4*>(kvb + ((size_t)ss * 64 + l) * 4);
      };
      auto PROC = [&](ushort4 kv, int i) {
        h2 a0 = attrS[wid][i][0], a1 = attrS[wid][i][1], a2 = attrS[wid][i][2],
           a3 = attrS[wid][i][3], a4 = attrS[wid][i][4];
        float ec0 = __builtin_amdgcn_fdot2(a0, wA[0], 0.f, false);
        ec0 = __builtin_amdgcn_fdot2(a1, wA[1], ec0, false);
        ec0 = __builtin_amdgcn_fdot2(a2, wA[2], ec0, false);
        ec0 = __builtin_amdgcn_fdot2(a3, wA[3], ec0, false);
        ec0 = __builtin_amdgcn_fdot2(a4, wA[4], ec0, false);
        float ec1 = __builtin_amdgcn_fdot2(a0, wB[0], 0.f, false);
        ec1 = __builtin_amdgcn_fdot2(a1, wB[1], ec1, false);
        ec1 = __builtin_amdgcn_fdot2(a2, wB[2], ec1, false);
        ec1 = __builtin_amdgcn_fdot2(a3, wB[3], ec1, false);
        ec1 = __builtin_amdgcn_fdot2(a4, wB[4], ec1, false);
        float kk0 = bf2f(kv.x) + ec0, kk1 = bf2f(kv.y) + ec1;
        float vv0 = bf2f(kv.z) + ec0, vv1 = bf2f(kv.w) + ec1;
        float p = fmaf(q0, kk0, q1 * kk1);
        p += __shfl_xor(p, 1, 8);
        p += __shfl_xor(p, 2, 8);
        p += __shfl_xor(p, 4, 8);
        if (__any(p > m + 8.f)) {
          float mn = fmaxf(m, p);
          float sc = __expf(m - mn);
          den *= sc; acc0 *= sc; acc1 *= sc;
          m = mn;
        }
        float ex = __expf(p - m);
        den += ex;
        acc0 = fmaf(ex, vv0, acc0);
        acc1 = fmaf(ex, vv1, acc1);
      };
      ushort4 kv0 = LD(0), kv1 = LD(1), kv2 = LD(2), kv3 = LD(3);
      for (int i = 0; i < cnt; i += 4) {
        ushort4 c0 = kv0, c1 = kv1, c2 = kv2, c3 = kv3;
        kv0 = LD(i + 4); kv1 = LD(i + 5); kv2 = LD(i + 6); kv3 = LD(i + 7);
        PROC(c0, i);
        if (i + 1 < cnt) PROC(c1, i + 1);
        if (i + 2 < cnt) PROC(c2, i + 2);
        if (i + 3 < cnt) PROC(c3, i + 3);
      }
    }
    float inv = 1.f / (den + 1e-16f);
    float oo0 = acc0 * inv, oo1 = acc1 * inv;
    float2 xr2 = *reinterpret_cast<const float2*>(xr + (size_t)node * D + d0);
    float2 x2 = *reinterpret_cast<const float2*>(x + (size_t)node * D + d0);
    float pb = oo0 * wb0.x + xr2.x * wb1.x + (oo0 - xr2.x) * wb2.x
             + oo1 * wb0.y + xr2.y * wb1.y + (oo1 - xr2.y) * wb2.y;
#pragma unroll
    for (int msk = 1; msk < 64; msk <<= 1) pb += __shfl_xor(pb, msk, 64);
    float beta = 1.f / (1.f + __expf(-pb));
    float h0 = x2.x + beta * xr2.x + (1.f - beta) * oo0;
    float h1 = x2.y + beta * xr2.y + (1.f - beta) * oo1;
    *reinterpret_cast<float2*>(h + (size_t)node * D + d0) = make_float2(h0, h1);
    s_h0 += h0; s_h20 += h0 * h0;
    s_h1 += h1; s_h21 += h1 * h1;
  }
  rs_h[wid * D + d0] = s_h0;   rs_h[wid * D + d0 + 1] = s_h1;
  rs_h2[wid * D + d0] = s_h20; rs_h2[wid * D + d0 + 1] = s_h21;
  __syncthreads();
  if (threadIdx.x < D) {
    int d = threadIdx.x;
    float sh = rs_h[d] + rs_h[D + d] + rs_h[2 * D + d] + rs_h[3 * D + d];
    float sh2 = rs_h2[d] + rs_h2[D + d] + rs_h2[2 * D + d] + rs_h2[3 * D + d];
    atomicAdd(&sums[d], sh);
    atomicAdd(&sums[D + d], sh2);
  }
}

// ---------------- kernel 6: fused GraphNorm-stats + FFN, LDS-staged ----------------
__global__ __launch_bounds__(256) void ffn_fused(
    const float* __restrict__ h, const float* __restrict__ sums,
    const float* __restrict__ gn_w, const float* __restrict__ gn_b,
    const float* __restrict__ gn_ms,
    const ushort* __restrict__ W1t, const float* __restrict__ b1,
    const ushort* __restrict__ W2t, const float* __restrict__ b2,
    float* __restrict__ out, float inv_n, int n) {
  __shared__ ushort xa[32 * XPAD];  // hn tile bf16, 8704 B
  __shared__ ushort tt[32 * TPAD];  // 33,280 B
  __shared__ float scsh[2 * D];
  // per-block recompute of GraphNorm scale/shift (saves a serial kernel)
  if (threadIdx.x < D) {
    int d = threadIdx.x;
    float mean = sums[d] * inv_n;
    float ex2 = sums[D + d] * inv_n;
    float ms = gn_ms[d];
    float var = ex2 - 2.f * ms * mean * mean + ms * ms * mean * mean;
    float inv = 1.f / sqrtf(var + 1e-5f);
    float scale = gn_w[d] * inv;
    scsh[d] = scale;
    scsh[D + d] = gn_b[d] - ms * mean * scale;
  }
  __syncthreads();
  int r0 = blockIdx.x * 32;
  // ---- stage hn tile [32][128] -> LDS bf16, coalesced ----
  {
    int row = threadIdx.x >> 3;
    int seg = threadIdx.x & 7;
    int grow = min(r0 + row, n - 1);
    const float4* p = reinterpret_cast<const float4*>(h + (size_t)grow * D + seg * 16);
    float4 f0 = p[0], f1 = p[1], f2 = p[2], f3 = p[3];
    const float4* sc = reinterpret_cast<const float4*>(scsh + seg * 16);
    const float4* sh = reinterpret_cast<const float4*>(scsh + D + seg * 16);
    float4 s0 = sc[0], s1 = sc[1], s2 = sc[2], s3 = sc[3];
    float4 t0 = sh[0], t1 = sh[1], t2 = sh[2], t3 = sh[3];
    bf16x8 u0, u1;
    u0[0] = (short)f2bf(f0.x * s0.x + t0.x); u0[1] = (short)f2bf(f0.y * s0.y + t0.y);
    u0[2] = (short)f2bf(f0.z * s0.z + t0.z); u0[3] = (short)f2bf(f0.w * s0.w + t0.w);
    u0[4] = (short)f2bf(f1.x * s1.x + t1.x); u0[5] = (short)f2bf(f1.y * s1.y + t1.y);
    u0[6] = (short)f2bf(f1.z * s1.z + t1.z); u0[7] = (short)f2bf(f1.w * s1.w + t1.w);
    u1[0] = (short)f2bf(f2.x * s2.x + t2.x); u1[1] = (short)f2bf(f2.y * s2.y + t2.y);
    u1[2] = (short)f2bf(f2.z * s2.z + t2.z); u1[3] = (short)f2bf(f2.w * s2.w + t2.w);
    u1[4] = (short)f2bf(f3.x * s3.x + t3.x); u1[5] = (short)f2bf(f3.y * s3.y + t3.y);
    u1[6] = (short)f2bf(f3.z * s3.z + t3.z); u1[7] = (short)f2bf(f3.w * s3.w + t3.w);
    ushort* dl = xa + row * XPAD + seg * 16;
    *reinterpret_cast<bf16x8*>(dl) = u0;
    *reinterpret_cast<bf16x8*>(dl + 8) = u1;
  }
  __syncthreads();
  int wv = threadIdx.x >> 6;
  int l = threadIdx.x & 63;
  int lr = l & 15, lg = l >> 4;
  int c0 = wv * 128;
  // ---- GEMM1: t = gelu(hn @ W1 + b1); this wave: cols [c0, c0+128) ----
  {
    f32x4 acc[2][8];
#pragma unroll
    for (int m = 0; m < 2; ++m)
#pragma unroll
      for (int nn = 0; nn < 8; ++nn) acc[m][nn] = (f32x4)0.f;
#pragma unroll
    for (int kb = 0; kb < 4; ++kb) {
      int k0 = kb * 32 + lg * 8;
      bf16x8 a[2];
#pragma unroll
      for (int m = 0; m < 2; ++m)
        a[m] = *reinterpret_cast<const bf16x8*>(xa + (m * 16 + lr) * XPAD + k0);
      bf16x8 b[8];
#pragma unroll
      for (int nn = 0; nn < 8; ++nn)
        b[nn] = *reinterpret_cast<const bf16x8*>(W1t + (c0 + nn * 16 + lr) * D + k0);
#pragma unroll
      for (int m = 0; m < 2; ++m)
#pragma unroll
        for (int nn = 0; nn < 8; ++nn)
          acc[m][nn] = __builtin_amdgcn_mfma_f32_16x16x32_bf16(a[m], b[nn], acc[m][nn], 0, 0, 0);
    }
    const float inv_sqrt2 = 0.70710678118654752440f;
#pragma unroll
    for (int m = 0; m < 2; ++m)
#pragma unroll
      for (int nn = 0; nn < 8; ++nn) {
        int col = c0 + nn * 16 + lr;
        float bb = b1[col];
#pragma unroll
        for (int j = 0; j < 4; ++j) {
          int rowl = m * 16 + lg * 4 + j;
          float val = acc[m][nn][j] + bb;
          val = 0.5f * val * (1.f + erff(val * inv_sqrt2));
          tt[rowl * TPAD + col] = f2bf(val);
        }
      }
  }
  __syncthreads();
  // ---- GEMM2: out = hn + t @ W2 + b2; this wave: cols [wv*32, wv*32+32) ----
  {
    f32x4 acc[2][2];
#pragma unroll
    for (int m = 0; m < 2; ++m)
#pragma unroll
      for (int nn = 0; nn < 2; ++nn) acc[m][nn] = (f32x4)0.f;
#pragma unroll 4
    for (int kb = 0; kb < 16; ++kb) {
      int k0 = kb * 32 + lg * 8;
      bf16x8 a[2];
#pragma unroll
      for (int m = 0; m < 2; ++m)
        a[m] = *reinterpret_cast<const bf16x8*>(tt + (m * 16 + lr) * TPAD + k0);
      bf16x8 b[2];
#pragma unroll
      for (int nn = 0; nn < 2; ++nn)
        b[nn] = *reinterpret_cast<const bf16x8*>(W2t + (wv * 32 + nn * 16 + lr) * FF + k0);
#pragma unroll
      for (int m = 0; m < 2; ++m)
#pragma unroll
        for (int nn = 0; nn < 2; ++nn)
          acc[m][nn] = __builtin_amdgcn_mfma_f32_16x16x32_bf16(a[m], b[nn], acc[m][nn], 0, 0, 0);
    }
#pragma unroll
    for (int m = 0; m < 2; ++m)
#pragma unroll
      for (int nn = 0; nn < 2; ++nn) {
        int col = wv * 32 + nn * 16 + lr;
        float bb = b2[col];
#pragma unroll
        for (int j = 0; j < 4; ++j) {
          int rowl = m * 16 + lg * 4 + j;
          int row = r0 + rowl;
          if (row < n) {
            float hn = bf2f(xa[rowl * XPAD + col]);
            out[(size_t)row * D + col] = hn + acc[m][nn][j] + bb;
          }
        }
      }
  }
}

extern "C" void kernel_launch(void* const* d_in, const int* in_sizes, int n_in,
                              void* d_out, int out_size, void* d_ws, size_t ws_size,
                              hipStream_t stream) {
  const float* x     = (const float*)d_in[0];
  const int*   ei    = (const int*)d_in[1];
  const float* attr  = (const float*)d_in[2];
  const float* Wq    = (const float*)d_in[3];
  const float* bq    = (const float*)d_in[4];
  const float* Wk    = (const float*)d_in[5];
  const float* bk    = (const float*)d_in[6];
  const float* Wv    = (const float*)d_in[7];
  const float* bv    = (const float*)d_in[8];
  const float* We    = (const float*)d_in[9];
  const float* Wskip = (const float*)d_in[10];
  const float* bskip = (const float*)d_in[11];
  const float* Wbeta = (const float*)d_in[12];
  const float* gn_w  = (const float*)d_in[13];
  const float* gn_b  = (const float*)d_in[14];
  const float* gn_ms = (const float*)d_in[15];
  const float* W1    = (const float*)d_in[16];
  const float* b1    = (const float*)d_in[17];
  const float* W2    = (const float*)d_in[18];
  const float* b2    = (const float*)d_in[19];

  const int n = in_sizes[0] / D;
  const int E = in_sizes[1] / 2;
  const int* src = ei;
  const int* dst = ei + E;
  const size_t ND = (size_t)n * D;

  // ---- workspace layout ----
  ushort* qb = (ushort*)d_ws;                 // ND bf16
  ushort* kvb = qb + ND;                      // 2*ND bf16
  float* xr = (float*)(kvb + 2 * ND);         // ND f32
  int* deg = (int*)(xr + ND);                 // n    (zeroed)
  float* sums = (float*)(deg + n);            // 2D   (zeroed)
  int* off = (int*)(sums + 2 * D);            // n+1
  int* sorted = off + n + 1;                  // E
  int* rank = sorted + E;                     // E
  ushort* Wcat_t = (ushort*)(rank + E);       // 4*D*D
  ushort* W1t = Wcat_t + 4 * D * D;           // D*FF
  ushort* W2t = W1t + D * FF;                 // FF*D
  float* bcat = (float*)(W2t + FF * D);       // 4D

  (void)hipMemsetAsync(deg, 0, ((size_t)n + 2 * D) * sizeof(int), stream);

  int ghist = (E + 255) / 256;
  prep_hist<<<256 + ghist, 256, 0, stream>>>(Wq, Wk, Wv, Wskip, bq, bk, bv, bskip, W1, W2,
                                             dst, deg, rank, E, Wcat_t, bcat, W1t, W2t);
  scan_kernel<<<1, 1024, 0, stream>>>(deg, off, n);
  scatter_kernel<<<ghist, 256, 0, stream>>>(dst, rank, off, sorted, E);

  gemm_in<<<(n + 31) / 32, 256, 0, stream>>>(x, Wcat_t, bcat, qb, kvb, xr, n);

  node_attn<<<2048, 256, 0, stream>>>(src, sorted, off, attr, We, qb, kvb, xr, x, Wbeta,
                                      (float*)d_out, sums, n);

  ffn_fused<<<(n + 31) / 32, 256, 0, stream>>>((const float*)d_out, sums, gn_w, gn_b, gn_ms,
                                               W1t, b1, W2t, b2, (float*)d_out,
                                               1.f / (float)n, n);
}

// Round 10
// 399.668 us; speedup vs baseline: 6.3009x; 1.0856x over previous
//
#include <hip/hip_runtime.h>
#include <hip/hip_fp16.h>
#include <math.h>

#define D 128
#define ED 10
#define FF 512
#define TPAD 520   // bf16 per LDS row in ffn t-tile (512 + 8 pad)
#define XPAD 136   // bf16 per LDS row for 128-wide tiles (128 + 8 pad)

typedef __attribute__((ext_vector_type(4))) float f32x4;
typedef __attribute__((ext_vector_type(8))) short bf16x8;
using h2 = decltype(__builtin_amdgcn_cvt_pkrtz(0.f, 0.f));  // __fp16 ext_vector(2)
typedef __attribute__((ext_vector_type(2))) float f32x2;

__device__ __forceinline__ ushort f2bf(float f) {
  unsigned u = __float_as_uint(f);
  unsigned r = u + 0x7fffu + ((u >> 16) & 1u);
  return (ushort)(r >> 16);
}
__device__ __forceinline__ float bf2f(ushort u) {
  return __uint_as_float(((unsigned)u) << 16);
}

// ---- fp8 e4m3 pack/unpack (hardware builtins with software fallback) ----
#if __has_builtin(__builtin_amdgcn_cvt_pk_f32_fp8) && __has_builtin(__builtin_amdgcn_cvt_pk_fp8_f32)
#define FP8_HW 1
#else
#define FP8_HW 0
#endif

__device__ __forceinline__ unsigned sw_f2fp8(float f) {  // e4m3fn, RNE-ish
  unsigned u = __float_as_uint(f);
  unsigned s = (u >> 24) & 0x80;
  int e = (int)((u >> 23) & 0xff) - 127;
  unsigned mant = u & 0x7fffff;
  if (e < -9) return s;  // underflow to 0
  if (e > 8) return s | 0x7e;  // clamp to max 448
  if (e >= -6) {
    unsigned m = mant + 0x7ffff + ((mant >> 20) & 1);
    if (m >= 0x800000) { m = 0; ++e; if (e > 8) return s | 0x7e; }
    return s | ((unsigned)(e + 7) << 3) | (m >> 20);
  }
  unsigned full = 0x800000 | mant;
  int shift = 20 + (-6 - e);
  unsigned m = (full + (1u << (shift - 1)) + ((full >> shift) & 1)) >> shift;
  if (m >= 8) return s | 0x08;
  return s | m;
}
__device__ __forceinline__ float sw_fp82f(unsigned b) {
  unsigned s = (b & 0x80) << 24;
  unsigned e = (b >> 3) & 0xf;
  unsigned m = b & 7;
  if (e == 0) {
    if (m == 0) return __uint_as_float(s);
    float v = (float)(int)m * 0.001953125f;  // m * 2^-9
    return (b & 0x80) ? -v : v;
  }
  return __uint_as_float(s | ((e + 120) << 23) | (m << 20));
}

__device__ __forceinline__ ushort pack_fp8_pair(float a, float b) {
#if FP8_HW
  int r = __builtin_amdgcn_cvt_pk_fp8_f32(a, b, 0, false);
  return (ushort)(r & 0xffff);
#else
  return (ushort)(sw_f2fp8(a) | (sw_f2fp8(b) << 8));
#endif
}
template <bool HI>
__device__ __forceinline__ f32x2 unpack_fp8_pair(unsigned w) {
#if FP8_HW
  auto r = __builtin_amdgcn_cvt_pk_f32_fp8((int)w, HI);
  f32x2 o; o[0] = r[0]; o[1] = r[1];
  return o;
#else
  unsigned v = HI ? (w >> 16) : w;
  f32x2 o; o[0] = sw_fp82f(v & 0xff); o[1] = sw_fp82f((v >> 8) & 0xff);
  return o;
#endif
}

// ---------------- kernel 1: weight prep (blocks 0..255) + degree hist + edge rank ------
__global__ void prep_hist(const float* __restrict__ Wq, const float* __restrict__ Wk,
                          const float* __restrict__ Wv, const float* __restrict__ Wskip,
                          const float* __restrict__ bq, const float* __restrict__ bk,
                          const float* __restrict__ bv, const float* __restrict__ bskip,
                          const float* __restrict__ W1, const float* __restrict__ W2,
                          const int* __restrict__ dst, int* __restrict__ deg,
                          int* __restrict__ rank, int E,
                          ushort* __restrict__ Wcat_t, float* __restrict__ bcat,
                          ushort* __restrict__ W1t, ushort* __restrict__ W2t) {
  int b = blockIdx.x;
  if (b >= 256) {
    int t = (b - 256) * 256 + threadIdx.x;
    if (t < E) rank[t] = atomicAdd(&deg[dst[t]], 1);
    return;
  }
  int t = b * 256 + threadIdx.x;  // 0..65535
  {
    int w = t >> 14, c = (t >> 7) & 127, kk = t & 127;
    const float* W = (w == 0) ? Wq : (w == 1) ? Wk : (w == 2) ? Wv : Wskip;
    Wcat_t[t] = f2bf(W[kk * D + c]);
  }
  {
    int f = t >> 7, kk = t & 127;
    W1t[t] = f2bf(W1[kk * FF + f]);
  }
  {
    int c = t >> 9, f = t & 511;
    W2t[t] = f2bf(W2[f * D + c]);
  }
  if (t < 4 * D) {
    int w = t >> 7;
    const float* bb = (w == 0) ? bq : (w == 1) ? bk : (w == 2) ? bv : bskip;
    bcat[t] = bb[t & 127];
  }
}

// ---------------- kernel 2: exclusive scan of deg -> off[0..n] ----------------
__global__ __launch_bounds__(1024) void scan_kernel(const int* __restrict__ deg,
                                                    int* __restrict__ off, int n) {
  __shared__ int part[1024];
  int t = threadIdx.x;
  int chunk = (n + 1023) / 1024;
  int lo = t * chunk, hi = min(lo + chunk, n);
  int s = 0;
  for (int i = lo; i < hi; ++i) s += deg[i];
  part[t] = s;
  __syncthreads();
  for (int dd = 1; dd < 1024; dd <<= 1) {
    int v = (t >= dd) ? part[t - dd] : 0;
    __syncthreads();
    part[t] += v;
    __syncthreads();
  }
  int excl = (t == 0) ? 0 : part[t - 1];
  for (int i = lo; i < hi; ++i) {
    off[i] = excl;
    excl += deg[i];
  }
  if (t == 1023) off[n] = part[1023];
}

// ---------------- kernel 3: CSR scatter (no atomics: rank precomputed) ----------------
__global__ void scatter_kernel(const int* __restrict__ dst, const int* __restrict__ rank,
                               const int* __restrict__ off, int* __restrict__ sorted, int E) {
  int t = blockIdx.x * blockDim.x + threadIdx.x;
  if (t >= E) return;
  sorted[off[dst[t]] + rank[t]] = t;
}

// ---------------- kernel 4: fused q/kv/xr GEMM, LDS-staged A, fp8 kv output ----------
__global__ __launch_bounds__(256) void gemm_in(
    const float* __restrict__ x, const ushort* __restrict__ Wcat_t,
    const float* __restrict__ bcat, ushort* __restrict__ qb, unsigned* __restrict__ kvf8,
    float* __restrict__ xr, int n) {
  __shared__ ushort xa[32 * XPAD];  // 8704 B
  int r0 = blockIdx.x * 32;
  {
    int row = threadIdx.x >> 3;   // 0..31
    int seg = threadIdx.x & 7;    // 16 floats each
    int grow = min(r0 + row, n - 1);
    const float4* p = reinterpret_cast<const float4*>(x + (size_t)grow * D + seg * 16);
    float4 f0 = p[0], f1 = p[1], f2 = p[2], f3 = p[3];
    bf16x8 u0, u1;
    u0[0] = (short)f2bf(f0.x); u0[1] = (short)f2bf(f0.y);
    u0[2] = (short)f2bf(f0.z); u0[3] = (short)f2bf(f0.w);
    u0[4] = (short)f2bf(f1.x); u0[5] = (short)f2bf(f1.y);
    u0[6] = (short)f2bf(f1.z); u0[7] = (short)f2bf(f1.w);
    u1[0] = (short)f2bf(f2.x); u1[1] = (short)f2bf(f2.y);
    u1[2] = (short)f2bf(f2.z); u1[3] = (short)f2bf(f2.w);
    u1[4] = (short)f2bf(f3.x); u1[5] = (short)f2bf(f3.y);
    u1[6] = (short)f2bf(f3.z); u1[7] = (short)f2bf(f3.w);
    ushort* dl = xa + row * XPAD + seg * 16;
    *reinterpret_cast<bf16x8*>(dl) = u0;
    *reinterpret_cast<bf16x8*>(dl + 8) = u1;
  }
  __syncthreads();
  int wv = threadIdx.x >> 6;
  int l = threadIdx.x & 63;
  int lr = l & 15, lg = l >> 4;
  const ushort* Wt = Wcat_t + wv * D * D;
  f32x4 acc[2][8];
#pragma unroll
  for (int m = 0; m < 2; ++m)
#pragma unroll
    for (int nn = 0; nn < 8; ++nn) acc[m][nn] = (f32x4)0.f;
#pragma unroll
  for (int kb2 = 0; kb2 < 4; ++kb2) {
    int k0 = kb2 * 32 + lg * 8;
    bf16x8 a[2];
#pragma unroll
    for (int m = 0; m < 2; ++m)
      a[m] = *reinterpret_cast<const bf16x8*>(xa + (m * 16 + lr) * XPAD + k0);
    bf16x8 b[8];
#pragma unroll
    for (int nn = 0; nn < 8; ++nn)
      b[nn] = *reinterpret_cast<const bf16x8*>(Wt + (nn * 16 + lr) * D + k0);
#pragma unroll
    for (int m = 0; m < 2; ++m)
#pragma unroll
      for (int nn = 0; nn < 8; ++nn)
        acc[m][nn] = __builtin_amdgcn_mfma_f32_16x16x32_bf16(a[m], b[nn], acc[m][nn], 0, 0, 0);
  }
#pragma unroll
  for (int m = 0; m < 2; ++m)
#pragma unroll
    for (int nn = 0; nn < 8; ++nn) {
      int col = nn * 16 + lr;
      float bb = bcat[wv * D + col];
#pragma unroll
      for (int j = 0; j < 4; ++j) {
        int row = r0 + m * 16 + lg * 4 + j;
        float val = acc[m][nn][j] + bb;
        if (wv == 1 || wv == 2) {
          // pack adjacent-column pair (cols live in adjacent lanes) as fp8
          float partner = __shfl_xor(val, 1, 64);
          if (((lr & 1) == 0) && row < n) {
            ushort us = pack_fp8_pair(val, partner);
            size_t idx = ((size_t)row * 64 + nn * 8 + (lr >> 1)) * 2 + (wv - 1);
            reinterpret_cast<ushort*>(kvf8)[idx] = us;
          }
        } else if (row < n) {
          if (wv == 0) qb[(size_t)row * D + col] = f2bf(val);
          else xr[(size_t)row * D + col] = val;
        }
      }
    }
}

// ---------------- kernel 5: node-centric attention, 4-deep pipelined, fp8 kv ----------
__global__ __launch_bounds__(256) void node_attn(
    const int* __restrict__ src, const int* __restrict__ sorted,
    const int* __restrict__ off, const float* __restrict__ attr,
    const float* __restrict__ We, const ushort* __restrict__ qb,
    const unsigned* __restrict__ kvf8, const float* __restrict__ xr,
    const float* __restrict__ x, const float* __restrict__ Wbeta,
    float* __restrict__ h, float* __restrict__ sums, int n) {
  __shared__ h2 attrS[4][64][5];
  __shared__ float rs_h[4 * D], rs_h2[4 * D];
  int wid = threadIdx.x >> 6;
  int l = threadIdx.x & 63;
  int d0 = 2 * l;
  h2 wA[5], wB[5];
#pragma unroll
  for (int t = 0; t < 5; ++t) {
    wA[t] = __builtin_amdgcn_cvt_pkrtz(We[(2 * t) * D + d0], We[(2 * t + 1) * D + d0]);
    wB[t] = __builtin_amdgcn_cvt_pkrtz(We[(2 * t) * D + d0 + 1], We[(2 * t + 1) * D + d0 + 1]);
  }
  float2 wb0 = *reinterpret_cast<const float2*>(Wbeta + d0);
  float2 wb1 = *reinterpret_cast<const float2*>(Wbeta + D + d0);
  float2 wb2 = *reinterpret_cast<const float2*>(Wbeta + 2 * D + d0);
  float s_h0 = 0.f, s_h20 = 0.f, s_h1 = 0.f, s_h21 = 0.f;
  for (int node = blockIdx.x * 4 + wid; node < n; node += gridDim.x * 4) {
    const ushort2 qu = *reinterpret_cast<const ushort2*>(qb + (size_t)node * D + d0);
    float q0 = bf2f(qu.x) * 0.25f, q1 = bf2f(qu.y) * 0.25f;
    int o0 = off[node], dg = off[node + 1] - o0;
    float m = -1e30f, den = 0.f, acc0 = 0.f, acc1 = 0.f;
    for (int chunk = 0; chunk < dg; chunk += 64) {
      int cnt = min(64, dg - chunk);
      int s_l = 0;
      {
        int e_l = 0;
        if (chunk + l < dg) {
          e_l = sorted[o0 + chunk + l];
          s_l = src[e_l];
        }
        const float2* ap = reinterpret_cast<const float2*>(attr + (size_t)e_l * ED);
#pragma unroll
        for (int j = 0; j < 5; ++j) {
          float2 av = ap[j];
          attrS[wid][l][j] = __builtin_amdgcn_cvt_pkrtz(av.x, av.y);
        }
      }
      auto LD = [&](int idx) -> unsigned {
        int ss = __shfl(s_l, min(idx, cnt - 1));
        return kvf8[(size_t)ss * 64 + l];
      };
      auto PROC = [&](unsigned kvw, int i) {
        h2 a0 = attrS[wid][i][0], a1 = attrS[wid][i][1], a2 = attrS[wid][i][2],
           a3 = attrS[wid][i][3], a4 = attrS[wid][i][4];
        float ec0 = __builtin_amdgcn_fdot2(a0, wA[0], 0.f, false);
        ec0 = __builtin_amdgcn_fdot2(a1, wA[1], ec0, false);
        ec0 = __builtin_amdgcn_fdot2(a2, wA[2], ec0, false);
        ec0 = __builtin_amdgcn_fdot2(a3, wA[3], ec0, false);
        ec0 = __builtin_amdgcn_fdot2(a4, wA[4], ec0, false);
        float ec1 = __builtin_amdgcn_fdot2(a0, wB[0], 0.f, false);
        ec1 = __builtin_amdgcn_fdot2(a1, wB[1], ec1, false);
        ec1 = __builtin_amdgcn_fdot2(a2, wB[2], ec1, false);
        ec1 = __builtin_amdgcn_fdot2(a3, wB[3], ec1, false);
        ec1 = __builtin_amdgcn_fdot2(a4, wB[4], ec1, false);
        f32x2 kf = unpack_fp8_pair<false>(kvw);
        f32x2 vf = unpack_fp8_pair<true>(kvw);
        float kk0 = kf[0] + ec0, kk1 = kf[1] + ec1;
        float vv0 = vf[0] + ec0, vv1 = vf[1] + ec1;
        float p = fmaf(q0, kk0, q1 * kk1);
        p += __shfl_xor(p, 1, 8);
        p += __shfl_xor(p, 2, 8);
        p += __shfl_xor(p, 4, 8);
        if (__any(p > m + 8.f)) {
          float mn = fmaxf(m, p);
          float sc = __expf(m - mn);
          den *= sc; acc0 *= sc; acc1 *= sc;
          m = mn;
        }
        float ex = __expf(p - m);
        den += ex;
        acc0 = fmaf(ex, vv0, acc0);
        acc1 = fmaf(ex, vv1, acc1);
      };
      unsigned kv0 = LD(0), kv1 = LD(1), kv2 = LD(2), kv3 = LD(3);
      for (int i = 0; i < cnt; i += 4) {
        unsigned c0 = kv0, c1 = kv1, c2 = kv2, c3 = kv3;
        kv0 = LD(i + 4); kv1 = LD(i + 5); kv2 = LD(i + 6); kv3 = LD(i + 7);
        PROC(c0, i);
        if (i + 1 < cnt) PROC(c1, i + 1);
        if (i + 2 < cnt) PROC(c2, i + 2);
        if (i + 3 < cnt) PROC(c3, i + 3);
      }
    }
    float inv = 1.f / (den + 1e-16f);
    float oo0 = acc0 * inv, oo1 = acc1 * inv;
    float2 xr2 = *reinterpret_cast<const float2*>(xr + (size_t)node * D + d0);
    float2 x2 = *reinterpret_cast<const float2*>(x + (size_t)node * D + d0);
    float pb = oo0 * wb0.x + xr2.x * wb1.x + (oo0 - xr2.x) * wb2.x
             + oo1 * wb0.y + xr2.y * wb1.y + (oo1 - xr2.y) * wb2.y;
#pragma unroll
    for (int msk = 1; msk < 64; msk <<= 1) pb += __shfl_xor(pb, msk, 64);
    float beta = 1.f / (1.f + __expf(-pb));
    float h0 = x2.x + beta * xr2.x + (1.f - beta) * oo0;
    float h1 = x2.y + beta * xr2.y + (1.f - beta) * oo1;
    *reinterpret_cast<float2*>(h + (size_t)node * D + d0) = make_float2(h0, h1);
    s_h0 += h0; s_h20 += h0 * h0;
    s_h1 += h1; s_h21 += h1 * h1;
  }
  rs_h[wid * D + d0] = s_h0;   rs_h[wid * D + d0 + 1] = s_h1;
  rs_h2[wid * D + d0] = s_h20; rs_h2[wid * D + d0 + 1] = s_h21;
  __syncthreads();
  if (threadIdx.x < D) {
    int d = threadIdx.x;
    float sh = rs_h[d] + rs_h[D + d] + rs_h[2 * D + d] + rs_h[3 * D + d];
    float sh2 = rs_h2[d] + rs_h2[D + d] + rs_h2[2 * D + d] + rs_h2[3 * D + d];
    atomicAdd(&sums[d], sh);
    atomicAdd(&sums[D + d], sh2);
  }
}

// ---------------- kernel 6: fused GraphNorm-stats + FFN, LDS-staged ----------------
__global__ __launch_bounds__(256) void ffn_fused(
    const float* __restrict__ h, const float* __restrict__ sums,
    const float* __restrict__ gn_w, const float* __restrict__ gn_b,
    const float* __restrict__ gn_ms,
    const ushort* __restrict__ W1t, const float* __restrict__ b1,
    const ushort* __restrict__ W2t, const float* __restrict__ b2,
    float* __restrict__ out, float inv_n, int n) {
  __shared__ ushort xa[32 * XPAD];
  __shared__ ushort tt[32 * TPAD];
  __shared__ float scsh[2 * D];
  if (threadIdx.x < D) {
    int d = threadIdx.x;
    float mean = sums[d] * inv_n;
    float ex2 = sums[D + d] * inv_n;
    float ms = gn_ms[d];
    float var = ex2 - 2.f * ms * mean * mean + ms * ms * mean * mean;
    float inv = 1.f / sqrtf(var + 1e-5f);
    float scale = gn_w[d] * inv;
    scsh[d] = scale;
    scsh[D + d] = gn_b[d] - ms * mean * scale;
  }
  __syncthreads();
  int r0 = blockIdx.x * 32;
  {
    int row = threadIdx.x >> 3;
    int seg = threadIdx.x & 7;
    int grow = min(r0 + row, n - 1);
    const float4* p = reinterpret_cast<const float4*>(h + (size_t)grow * D + seg * 16);
    float4 f0 = p[0], f1 = p[1], f2 = p[2], f3 = p[3];
    const float4* sc = reinterpret_cast<const float4*>(scsh + seg * 16);
    const float4* sh = reinterpret_cast<const float4*>(scsh + D + seg * 16);
    float4 s0 = sc[0], s1 = sc[1], s2 = sc[2], s3 = sc[3];
    float4 t0 = sh[0], t1 = sh[1], t2 = sh[2], t3 = sh[3];
    bf16x8 u0, u1;
    u0[0] = (short)f2bf(f0.x * s0.x + t0.x); u0[1] = (short)f2bf(f0.y * s0.y + t0.y);
    u0[2] = (short)f2bf(f0.z * s0.z + t0.z); u0[3] = (short)f2bf(f0.w * s0.w + t0.w);
    u0[4] = (short)f2bf(f1.x * s1.x + t1.x); u0[5] = (short)f2bf(f1.y * s1.y + t1.y);
    u0[6] = (short)f2bf(f1.z * s1.z + t1.z); u0[7] = (short)f2bf(f1.w * s1.w + t1.w);
    u1[0] = (short)f2bf(f2.x * s2.x + t2.x); u1[1] = (short)f2bf(f2.y * s2.y + t2.y);
    u1[2] = (short)f2bf(f2.z * s2.z + t2.z); u1[3] = (short)f2bf(f2.w * s2.w + t2.w);
    u1[4] = (short)f2bf(f3.x * s3.x + t3.x); u1[5] = (short)f2bf(f3.y * s3.y + t3.y);
    u1[6] = (short)f2bf(f3.z * s3.z + t3.z); u1[7] = (short)f2bf(f3.w * s3.w + t3.w);
    ushort* dl = xa + row * XPAD + seg * 16;
    *reinterpret_cast<bf16x8*>(dl) = u0;
    *reinterpret_cast<bf16x8*>(dl + 8) = u1;
  }
  __syncthreads();
  int wv = threadIdx.x >> 6;
  int l = threadIdx.x & 63;
  int lr = l & 15, lg = l >> 4;
  int c0 = wv * 128;
  {
    f32x4 acc[2][8];
#pragma unroll
    for (int m = 0; m < 2; ++m)
#pragma unroll
      for (int nn = 0; nn < 8; ++nn) acc[m][nn] = (f32x4)0.f;
#pragma unroll
    for (int kb = 0; kb < 4; ++kb) {
      int k0 = kb * 32 + lg * 8;
      bf16x8 a[2];
#pragma unroll
      for (int m = 0; m < 2; ++m)
        a[m] = *reinterpret_cast<const bf16x8*>(xa + (m * 16 + lr) * XPAD + k0);
      bf16x8 b[8];
#pragma unroll
      for (int nn = 0; nn < 8; ++nn)
        b[nn] = *reinterpret_cast<const bf16x8*>(W1t + (c0 + nn * 16 + lr) * D + k0);
#pragma unroll
      for (int m = 0; m < 2; ++m)
#pragma unroll
        for (int nn = 0; nn < 8; ++nn)
          acc[m][nn] = __builtin_amdgcn_mfma_f32_16x16x32_bf16(a[m], b[nn], acc[m][nn], 0, 0, 0);
    }
    const float inv_sqrt2 = 0.70710678118654752440f;
#pragma unroll
    for (int m = 0; m < 2; ++m)
#pragma unroll
      for (int nn = 0; nn < 8; ++nn) {
        int col = c0 + nn * 16 + lr;
        float bb = b1[col];
#pragma unroll
        for (int j = 0; j < 4; ++j) {
          int rowl = m * 16 + lg * 4 + j;
          float val = acc[m][nn][j] + bb;
          val = 0.5f * val * (1.f + erff(val * inv_sqrt2));
          tt[rowl * TPAD + col] = f2bf(val);
        }
      }
  }
  __syncthreads();
  {
    f32x4 acc[2][2];
#pragma unroll
    for (int m = 0; m < 2; ++m)
#pragma unroll
      for (int nn = 0; nn < 2; ++nn) acc[m][nn] = (f32x4)0.f;
#pragma unroll 4
    for (int kb = 0; kb < 16; ++kb) {
      int k0 = kb * 32 + lg * 8;
      bf16x8 a[2];
#pragma unroll
      for (int m = 0; m < 2; ++m)
        a[m] = *reinterpret_cast<const bf16x8*>(tt + (m * 16 + lr) * TPAD + k0);
      bf16x8 b[2];
#pragma unroll
      for (int nn = 0; nn < 2; ++nn)
        b[nn] = *reinterpret_cast<const bf16x8*>(W2t + (wv * 32 + nn * 16 + lr) * FF + k0);
#pragma unroll
      for (int m = 0; m < 2; ++m)
#pragma unroll
        for (int nn = 0; nn < 2; ++nn)
          acc[m][nn] = __builtin_amdgcn_mfma_f32_16x16x32_bf16(a[m], b[nn], acc[m][nn], 0, 0, 0);
    }
#pragma unroll
    for (int m = 0; m < 2; ++m)
#pragma unroll
      for (int nn = 0; nn < 2; ++nn) {
        int col = wv * 32 + nn * 16 + lr;
        float bb = b2[col];
#pragma unroll
        for (int j = 0; j < 4; ++j) {
          int rowl = m * 16 + lg * 4 + j;
          int row = r0 + rowl;
          if (row < n) {
            float hn = bf2f(xa[rowl * XPAD + col]);
            out[(size_t)row * D + col] = hn + acc[m][nn][j] + bb;
          }
        }
      }
  }
}

extern "C" void kernel_launch(void* const* d_in, const int* in_sizes, int n_in,
                              void* d_out, int out_size, void* d_ws, size_t ws_size,
                              hipStream_t stream) {
  const float* x     = (const float*)d_in[0];
  const int*   ei    = (const int*)d_in[1];
  const float* attr  = (const float*)d_in[2];
  const float* Wq    = (const float*)d_in[3];
  const float* bq    = (const float*)d_in[4];
  const float* Wk    = (const float*)d_in[5];
  const float* bk    = (const float*)d_in[6];
  const float* Wv    = (const float*)d_in[7];
  const float* bv    = (const float*)d_in[8];
  const float* We    = (const float*)d_in[9];
  const float* Wskip = (const float*)d_in[10];
  const float* bskip = (const float*)d_in[11];
  const float* Wbeta = (const float*)d_in[12];
  const float* gn_w  = (const float*)d_in[13];
  const float* gn_b  = (const float*)d_in[14];
  const float* gn_ms = (const float*)d_in[15];
  const float* W1    = (const float*)d_in[16];
  const float* b1    = (const float*)d_in[17];
  const float* W2    = (const float*)d_in[18];
  const float* b2    = (const float*)d_in[19];

  const int n = in_sizes[0] / D;
  const int E = in_sizes[1] / 2;
  const int* src = ei;
  const int* dst = ei + E;
  const size_t ND = (size_t)n * D;

  // ---- workspace layout ----
  ushort* qb = (ushort*)d_ws;                 // ND bf16
  unsigned* kvf8 = (unsigned*)(qb + ND);      // n*64 uints (fp8 k/v interleaved)
  float* xr = (float*)(kvf8 + (size_t)n * 64);// ND f32
  int* deg = (int*)(xr + ND);                 // n    (zeroed)
  float* sums = (float*)(deg + n);            // 2D   (zeroed)
  int* off = (int*)(sums + 2 * D);            // n+1
  int* sorted = off + n + 1;                  // E
  int* rank = sorted + E;                     // E
  ushort* Wcat_t = (ushort*)(rank + E);       // 4*D*D
  ushort* W1t = Wcat_t + 4 * D * D;           // D*FF
  ushort* W2t = W1t + D * FF;                 // FF*D
  float* bcat = (float*)(W2t + FF * D);       // 4D

  (void)hipMemsetAsync(deg, 0, ((size_t)n + 2 * D) * sizeof(int), stream);

  int ghist = (E + 255) / 256;
  prep_hist<<<256 + ghist, 256, 0, stream>>>(Wq, Wk, Wv, Wskip, bq, bk, bv, bskip, W1, W2,
                                             dst, deg, rank, E, Wcat_t, bcat, W1t, W2t);
  scan_kernel<<<1, 1024, 0, stream>>>(deg, off, n);
  scatter_kernel<<<ghist, 256, 0, stream>>>(dst, rank, off, sorted, E);

  gemm_in<<<(n + 31) / 32, 256, 0, stream>>>(x, Wcat_t, bcat, qb, kvf8, xr, n);

  node_attn<<<2048, 256, 0, stream>>>(src, sorted, off, attr, We, qb, kvf8, xr, x, Wbeta,
                                      (float*)d_out, sums, n);

  ffn_fused<<<(n + 31) / 32, 256, 0, stream>>>((const float*)d_out, sums, gn_w, gn_b, gn_ms,
                                               W1t, b1, W2t, b2, (float*)d_out,
                                               1.f / (float)n, n);
}